// Round 15
// baseline (384.902 us; speedup 1.0000x reference)
//
#include <hip/hip_runtime.h>
#include <cstdint>
#include <cstddef>

#define ROWS 27648
#define NEGV (-1e10f)

typedef __attribute__((ext_vector_type(8))) short bf16x8;
typedef __attribute__((ext_vector_type(8))) short short8;
typedef __attribute__((ext_vector_type(4))) short short4v;
typedef __attribute__((ext_vector_type(4))) float f32x4;
typedef __attribute__((ext_vector_type(4), aligned(4))) float f32x4u;  // 4B-aligned vector load

__device__ __forceinline__ float sigmoidf_(float x) { return 1.f / (1.f + __expf(-x)); }
__device__ __forceinline__ float bf2f(short s) {
  union { float f; unsigned u; } x; x.u = ((unsigned)(unsigned short)s) << 16; return x.f;
}
__device__ __forceinline__ short f2bf(float f) {   // RNE
  union { float f; unsigned u; } x; x.f = f;
  unsigned r = (x.u + 0x7fffu + ((x.u >> 16) & 1u)) >> 16;
  return (short)r;
}

// ---------------------------------------------------------------------------
// bf16 MFMA GEMM r11: BK=64, swizzled LDS (validated r5: -11us total).
// ---------------------------------------------------------------------------
#define GLDS(gp, lp) __builtin_amdgcn_global_load_lds( \
  (const __attribute__((address_space(1))) void*)(gp), \
  (__attribute__((address_space(3))) void*)(lp), 16, 0, 0)

template <int ACT, int BF16OUT>
__global__ __launch_bounds__(256) void gemm_mfma(
    const short* __restrict__ A, int lda,
    const short* __restrict__ B, int ldb,
    const float* __restrict__ bias,
    void* __restrict__ Cv, int ldc, int nstore, int K) {
  extern __shared__ short smem[];
  short* As = smem;              // [128][64] swizzled, 16 KB
  short* Bs = smem + 8192;       // [128][64] swizzled, 16 KB
  const int tid = threadIdx.x;
  const int wave = tid >> 6, lane = tid & 63;
  const int m0 = blockIdx.x * 128, n0 = blockIdx.y * 128;
  const int srow = lane >> 3;                    // 0..7 within 8-row GLDS group
  const int scol = ((lane & 7) ^ srow) * 8;      // swizzled 16B chunk (shorts)
  const int sr0 = wave * 32;
  const int wm = (wave >> 1) * 64, wn = (wave & 1) * 64;
  const int fr = lane & 15, fk = (lane >> 4) * 8;

  f32x4 acc[4][4] = {};

  const short* pA = A + (size_t)(m0 + sr0 + srow) * lda + scol;
  const short* pB = B + (size_t)(n0 + sr0 + srow) * ldb + scol;
  short* lA = &As[sr0 * 64];
  short* lB = &Bs[sr0 * 64];

  const int KB = K & ~63;
  for (int k0 = 0; k0 < KB; k0 += 64) {
#pragma unroll
    for (int g = 0; g < 4; ++g) {
      GLDS(pA + k0 + g * 8 * lda, lA + g * 512);
      GLDS(pB + k0 + g * 8 * ldb, lB + g * 512);
    }
    __syncthreads();
#pragma unroll
    for (int ks = 0; ks < 2; ++ks) {
      bf16x8 af[4], bfr[4];
#pragma unroll
      for (int t = 0; t < 4; ++t) {
        const int ra = wm + t * 16 + fr;
        const int rb = wn + t * 16 + fr;
        af[t]  = *(const bf16x8*)&As[(ra * 64 + ks * 32 + fk) ^ ((ra & 7) << 3)];
        bfr[t] = *(const bf16x8*)&Bs[(rb * 64 + ks * 32 + fk) ^ ((rb & 7) << 3)];
      }
#pragma unroll
      for (int i = 0; i < 4; ++i)
#pragma unroll
        for (int j = 0; j < 4; ++j)
          acc[i][j] = __builtin_amdgcn_mfma_f32_16x16x32_bf16(af[i], bfr[j], acc[i][j], 0, 0, 0);
    }
    __syncthreads();
  }

  if (K & 32) {                  // 32-wide tail: separate linear buffers
    short* As2 = smem + 16384;   // [128][32], 8 KB
    short* Bs2 = smem + 20480;   // [128][32], 8 KB
    const int sr2 = lane >> 2, sc2 = (lane & 3) * 8;
    const short* qA = A + (size_t)(m0 + sr0 + sr2) * lda + sc2 + KB;
    const short* qB = B + (size_t)(n0 + sr0 + sr2) * ldb + sc2 + KB;
    GLDS(qA, &As2[sr0 * 32]);
    GLDS(qA + 16 * lda, &As2[(sr0 + 16) * 32]);
    GLDS(qB, &Bs2[sr0 * 32]);
    GLDS(qB + 16 * ldb, &Bs2[(sr0 + 16) * 32]);
    __syncthreads();
    bf16x8 af[4], bfr[4];
#pragma unroll
    for (int t = 0; t < 4; ++t) {
      af[t]  = *(const bf16x8*)&As2[(wm + t * 16 + fr) * 32 + fk];
      bfr[t] = *(const bf16x8*)&Bs2[(wn + t * 16 + fr) * 32 + fk];
    }
#pragma unroll
    for (int i = 0; i < 4; ++i)
#pragma unroll
      for (int j = 0; j < 4; ++j)
        acc[i][j] = __builtin_amdgcn_mfma_f32_16x16x32_bf16(af[i], bfr[j], acc[i][j], 0, 0, 0);
  }

  const int rbase = m0 + wm + (lane >> 4) * 4;
#pragma unroll
  for (int j = 0; j < 4; ++j) {
    const int col = n0 + wn + j * 16 + fr;
    if (col >= nstore) continue;
    const float bv = bias ? bias[col] : 0.f;
#pragma unroll
    for (int i = 0; i < 4; ++i)
#pragma unroll
      for (int r = 0; r < 4; ++r) {
        const int row = rbase + i * 16 + r;
        float v = acc[i][j][r] + bv;
        if (ACT) v = fmaxf(v, 0.f);
        if (BF16OUT) ((short*)Cv)[(size_t)row * ldc + col] = f2bf(v);
        else         ((float*)Cv)[(size_t)row * ldc + col] = v;
      }
  }
}

// ---------------------------------------------------------------------------
// r19: GI and GH GEMMs merged in one dispatch (validated r14: -14us).
// blockIdx.y < 6 -> GI = X @ Wih^T + bih; else GH = hidden @ Whh^T + bhh.
// ---------------------------------------------------------------------------
__global__ __launch_bounds__(256) void gemm_gigh(
    const short* __restrict__ XB, const short* __restrict__ HIDB,
    const short* __restrict__ WIH, const short* __restrict__ WHH,
    const float* __restrict__ bih, const float* __restrict__ bhh,
    short* __restrict__ GI, short* __restrict__ GH) {
  extern __shared__ short smem[];
  short* As = smem;
  short* Bs = smem + 8192;
  const int tid = threadIdx.x;
  const int wave = tid >> 6, lane = tid & 63;
  const int half = (blockIdx.y >= 6);
  const int m0 = blockIdx.x * 128;
  const int n0 = (blockIdx.y - (half ? 6 : 0)) * 128;
  const short* A = half ? HIDB : XB;
  const short* B = half ? WHH : WIH;
  const float* bias = half ? bhh : bih;
  short* C = half ? GH : GI;
  const int srow = lane >> 3;
  const int scol = ((lane & 7) ^ srow) * 8;
  const int sr0 = wave * 32;
  const int wm = (wave >> 1) * 64, wn = (wave & 1) * 64;
  const int fr = lane & 15, fk = (lane >> 4) * 8;

  f32x4 acc[4][4] = {};
  const short* pA = A + (size_t)(m0 + sr0 + srow) * 256 + scol;
  const short* pB = B + (size_t)(n0 + sr0 + srow) * 256 + scol;
  short* lA = &As[sr0 * 64];
  short* lB = &Bs[sr0 * 64];

  for (int k0 = 0; k0 < 256; k0 += 64) {
#pragma unroll
    for (int g = 0; g < 4; ++g) {
      GLDS(pA + k0 + g * 8 * 256, lA + g * 512);
      GLDS(pB + k0 + g * 8 * 256, lB + g * 512);
    }
    __syncthreads();
#pragma unroll
    for (int ks = 0; ks < 2; ++ks) {
      bf16x8 af[4], bfr[4];
#pragma unroll
      for (int t = 0; t < 4; ++t) {
        const int ra = wm + t * 16 + fr;
        const int rb = wn + t * 16 + fr;
        af[t]  = *(const bf16x8*)&As[(ra * 64 + ks * 32 + fk) ^ ((ra & 7) << 3)];
        bfr[t] = *(const bf16x8*)&Bs[(rb * 64 + ks * 32 + fk) ^ ((rb & 7) << 3)];
      }
#pragma unroll
      for (int i = 0; i < 4; ++i)
#pragma unroll
        for (int j = 0; j < 4; ++j)
          acc[i][j] = __builtin_amdgcn_mfma_f32_16x16x32_bf16(af[i], bfr[j], acc[i][j], 0, 0, 0);
    }
    __syncthreads();
  }

  const int rbase = m0 + wm + (lane >> 4) * 4;
#pragma unroll
  for (int j = 0; j < 4; ++j) {
    const int col = n0 + wn + j * 16 + fr;
    const float bv = bias[col];
#pragma unroll
    for (int i = 0; i < 4; ++i)
#pragma unroll
      for (int r = 0; r < 4; ++r) {
        const int row = rbase + i * 16 + r;
        C[(size_t)row * 768 + col] = f2bf(acc[i][j][r] + bv);
      }
  }
}

// ---------------------------------------------------------------------------
// Split-output GEMM for [P1 | QK] (BK=64 swizzled, K=256, no tail).
// ---------------------------------------------------------------------------
__global__ __launch_bounds__(256) void gemm_pqk(
    const short* __restrict__ A, const short* __restrict__ B,
    const float* __restrict__ bias,
    short* __restrict__ P1, float* __restrict__ QK) {
  extern __shared__ short smem[];
  short* As = smem;
  short* Bs = smem + 8192;
  const int tid = threadIdx.x;
  const int wave = tid >> 6, lane = tid & 63;
  const int m0 = blockIdx.x * 128, n0 = blockIdx.y * 128;
  const int srow = lane >> 3;
  const int scol = ((lane & 7) ^ srow) * 8;
  const int sr0 = wave * 32;
  const int wm = (wave >> 1) * 64, wn = (wave & 1) * 64;
  const int fr = lane & 15, fk = (lane >> 4) * 8;

  f32x4 acc[4][4] = {};
  const short* pA = A + (size_t)(m0 + sr0 + srow) * 288 + scol;
  const short* pB = B + (size_t)(n0 + sr0 + srow) * 256 + scol;
  short* lA = &As[sr0 * 64];
  short* lB = &Bs[sr0 * 64];

  for (int k0 = 0; k0 < 256; k0 += 64) {
#pragma unroll
    for (int g = 0; g < 4; ++g) {
      GLDS(pA + k0 + g * 8 * 288, lA + g * 512);
      GLDS(pB + k0 + g * 8 * 256, lB + g * 512);
    }
    __syncthreads();
#pragma unroll
    for (int ks = 0; ks < 2; ++ks) {
      bf16x8 af[4], bfr[4];
#pragma unroll
      for (int t = 0; t < 4; ++t) {
        const int ra = wm + t * 16 + fr;
        const int rb = wn + t * 16 + fr;
        af[t]  = *(const bf16x8*)&As[(ra * 64 + ks * 32 + fk) ^ ((ra & 7) << 3)];
        bfr[t] = *(const bf16x8*)&Bs[(rb * 64 + ks * 32 + fk) ^ ((rb & 7) << 3)];
      }
#pragma unroll
      for (int i = 0; i < 4; ++i)
#pragma unroll
        for (int j = 0; j < 4; ++j)
          acc[i][j] = __builtin_amdgcn_mfma_f32_16x16x32_bf16(af[i], bfr[j], acc[i][j], 0, 0, 0);
    }
    __syncthreads();
  }

  const int rbase = m0 + wm + (lane >> 4) * 4;
#pragma unroll
  for (int j = 0; j < 4; ++j) {
    const int col = n0 + wn + j * 16 + fr;
    if (col >= 384) continue;
    const float bv = bias[col];
#pragma unroll
    for (int i = 0; i < 4; ++i)
#pragma unroll
      for (int r = 0; r < 4; ++r) {
        const int row = rbase + i * 16 + r;
        float v = acc[i][j][r] + bv;
        if (col < 256) {
          P1[(size_t)row * 256 + col] = f2bf(fmaxf(v, 0.f));
        } else {
          QK[(size_t)row * 128 + (col - 256)] = v;
        }
      }
  }
}

// ---------------------------------------------------------------------------
// r16: logits GEMM (K=256, N=33) + FUSED sv epilogue. Grid (216).
// ---------------------------------------------------------------------------
__global__ __launch_bounds__(256) void gemm_logits_sv(
    const short* __restrict__ A, const short* __restrict__ B,
    const float* __restrict__ bias,
    const float* __restrict__ Wv, const float* __restrict__ bv,
    float* __restrict__ LOG, float* __restrict__ SV) {
  extern __shared__ short smem[];
  short* As = smem;
  short* Bs = smem + 8192;
  const int tid = threadIdx.x;
  const int wave = tid >> 6, lane = tid & 63;
  const int m0 = blockIdx.x * 128;
  const int srow = lane >> 3;
  const int scol = ((lane & 7) ^ srow) * 8;
  const int sr0 = wave * 32;
  const int wm = (wave >> 1) * 64, wn = (wave & 1) * 64;
  const int fr = lane & 15, fk = (lane >> 4) * 8;

  f32x4 acc[4][4] = {};
  const short* pA = A + (size_t)(m0 + sr0 + srow) * 256 + scol;
  const short* pB = B + (size_t)(sr0 + srow) * 256 + scol;
  short* lA = &As[sr0 * 64];
  short* lB = &Bs[sr0 * 64];

  for (int k0 = 0; k0 < 256; k0 += 64) {
#pragma unroll
    for (int g = 0; g < 4; ++g) {
      GLDS(pA + k0 + g * 8 * 256, lA + g * 512);
      GLDS(pB + k0 + g * 8 * 256, lB + g * 512);
    }
    __syncthreads();
#pragma unroll
    for (int ks = 0; ks < 2; ++ks) {
      bf16x8 af[4], bfr[4];
#pragma unroll
      for (int t = 0; t < 4; ++t) {
        const int ra = wm + t * 16 + fr;
        const int rb = wn + t * 16 + fr;
        af[t]  = *(const bf16x8*)&As[(ra * 64 + ks * 32 + fk) ^ ((ra & 7) << 3)];
        bfr[t] = *(const bf16x8*)&Bs[(rb * 64 + ks * 32 + fk) ^ ((rb & 7) << 3)];
      }
#pragma unroll
      for (int i = 0; i < 4; ++i)
#pragma unroll
        for (int j = 0; j < 4; ++j)
          acc[i][j] = __builtin_amdgcn_mfma_f32_16x16x32_bf16(af[i], bfr[j], acc[i][j], 0, 0, 0);
    }
    __syncthreads();
  }

  // ---- epilogue: store LOG + stage tile in LDS (32KB free now) ----
  float* ls = (float*)smem;              // [128][33]
  const int rloc = wm + (lane >> 4) * 4; // local row base
  if (wn == 0) {
#pragma unroll
    for (int j = 0; j < 3; ++j) {
      const int col = j * 16 + fr;
      if (col < 33) {
        const float bvv = bias[col];
#pragma unroll
        for (int i = 0; i < 4; ++i)
#pragma unroll
          for (int r = 0; r < 4; ++r) {
            const int row = rloc + i * 16 + r;
            const float v = acc[i][j][r] + bvv;
            LOG[(size_t)(m0 + row) * 33 + col] = v;
            ls[row * 33 + col] = v;
          }
      }
    }
  }
  __syncthreads();

  // ---- sv: one thread per row ----
  if (tid < 128) {
    const float* base = &ls[tid * 33];
    float m = base[6];
#pragma unroll
    for (int c = 7; c < 33; ++c) m = fmaxf(m, base[c]);
    float p[27], s = 0.f;
#pragma unroll
    for (int c = 0; c < 27; ++c) { p[c] = __expf(base[6 + c] - m); s += p[c]; }
    const float inv = 1.f / s;
    float vs[29];
#pragma unroll
    for (int c = 0; c < 27; ++c) vs[c] = p[c] * inv;
    vs[27] = 1.f;
    vs[28] = inv;                        // top1 = max prob
    float* outp = SV + (size_t)(m0 + tid) * 32;
#pragma unroll
    for (int o4 = 0; o4 < 8; ++o4) {
      f32x4 ov;
#pragma unroll
      for (int e = 0; e < 4; ++e) {
        const int o = o4 * 4 + e;
        float acc2 = bv[o];
        const float* w = Wv + o * 29;
#pragma unroll
        for (int c = 0; c < 29; ++c) acc2 += w[c] * vs[c];
        ov[e] = acc2;
      }
      *(f32x4*)(outp + o4 * 4) = ov;
    }
  }
}

// ---------------------------------------------------------------------------
// r16: GDf GEMM (K=512, N=28) + FUSED final-fuse epilogue. Grid (216).
// ---------------------------------------------------------------------------
__global__ __launch_bounds__(256) void gemm_gdf_fuse(
    const short* __restrict__ A, const short* __restrict__ B,
    const float* __restrict__ bias,
    const float* __restrict__ LOG, float* __restrict__ out) {
  extern __shared__ short smem[];
  short* As = smem;
  short* Bs = smem + 8192;
  const int tid = threadIdx.x;
  const int wave = tid >> 6, lane = tid & 63;
  const int m0 = blockIdx.x * 128;
  const int srow = lane >> 3;
  const int scol = ((lane & 7) ^ srow) * 8;
  const int sr0 = wave * 32;
  const int wm = (wave >> 1) * 64, wn = (wave & 1) * 64;
  const int fr = lane & 15, fk = (lane >> 4) * 8;

  f32x4 acc[4][4] = {};
  const short* pA = A + (size_t)(m0 + sr0 + srow) * 512 + scol;
  const short* pB = B + (size_t)(sr0 + srow) * 512 + scol;
  short* lA = &As[sr0 * 64];
  short* lB = &Bs[sr0 * 64];

  for (int k0 = 0; k0 < 512; k0 += 64) {
#pragma unroll
    for (int g = 0; g < 4; ++g) {
      GLDS(pA + k0 + g * 8 * 512, lA + g * 512);
      GLDS(pB + k0 + g * 8 * 512, lB + g * 512);
    }
    __syncthreads();
#pragma unroll
    for (int ks = 0; ks < 2; ++ks) {
      bf16x8 af[4], bfr[4];
#pragma unroll
      for (int t = 0; t < 4; ++t) {
        const int ra = wm + t * 16 + fr;
        const int rb = wn + t * 16 + fr;
        af[t]  = *(const bf16x8*)&As[(ra * 64 + ks * 32 + fk) ^ ((ra & 7) << 3)];
        bfr[t] = *(const bf16x8*)&Bs[(rb * 64 + ks * 32 + fk) ^ ((rb & 7) << 3)];
      }
#pragma unroll
      for (int i = 0; i < 4; ++i)
#pragma unroll
        for (int j = 0; j < 4; ++j)
          acc[i][j] = __builtin_amdgcn_mfma_f32_16x16x32_bf16(af[i], bfr[j], acc[i][j], 0, 0, 0);
    }
    __syncthreads();
  }

  // ---- epilogue: stage GDf tile [128][28] in LDS ----
  float* ls = (float*)smem;
  const int rloc = wm + (lane >> 4) * 4;
  if (wn == 0) {
#pragma unroll
    for (int j = 0; j < 2; ++j) {
      const int col = j * 16 + fr;
      if (col < 28) {
        const float bvv = bias[col];
#pragma unroll
        for (int i = 0; i < 4; ++i)
#pragma unroll
          for (int r = 0; r < 4; ++r) {
            const int row = rloc + i * 16 + r;
            ls[row * 28 + col] = acc[i][j][r] + bvv;
          }
      }
    }
  }
  __syncthreads();

  // ---- fuse: out[row, 0..32] = LOG +/- 0.1 * gate * delta ----
  for (int idx = tid; idx < 128 * 33; idx += 256) {
    const int row = idx / 33;
    const int c = idx - row * 33;
    float v = LOG[(size_t)(m0 + row) * 33 + c];
    if (c >= 6) {
      const float gate = sigmoidf_(ls[row * 28]);
      v += 0.1f * gate * ls[row * 28 + (c - 5)];
    }
    out[(size_t)(m0 + row) * 33 + c] = v;
  }
}

// ---------------------------------------------------------------------------
// Combined activation + weight conversion r15: 8-wide vectorized big regions.
// ---------------------------------------------------------------------------
__global__ __launch_bounds__(256) void conv_all(
    const float* __restrict__ inputs, const float* __restrict__ hidden,
    const float* __restrict__ W1, const float* __restrict__ Wih,
    const float* __restrict__ Whh, const float* __restrict__ Wp1,
    const float* __restrict__ Wp2, const float* __restrict__ Wq,
    const float* __restrict__ Wk, const float* __restrict__ Wg1,
    const float* __restrict__ Wd1, const float* __restrict__ Wg2,
    const float* __restrict__ Wd2, const float* __restrict__ bp1,
    const float* __restrict__ bq, const float* __restrict__ bg1,
    const float* __restrict__ bd1, const float* __restrict__ bg2,
    const float* __restrict__ bd2,
    short* __restrict__ xin, short* __restrict__ hid,
    short* __restrict__ w1w, short* __restrict__ wihw, short* __restrict__ whhw,
    short* __restrict__ wp2w, short* __restrict__ wpqk, short* __restrict__ wgdw,
    short* __restrict__ wfw, float* __restrict__ bpqkb, float* __restrict__ bgd,
    float* __restrict__ bf2v) {
  int idx = blockIdx.x * 256 + threadIdx.x;
  // ---- XIN 8-wide: rows of 352 = 44 chunks; src row stride 322 (8B align) --
  if (idx < ROWS * 44) {
    const int row = idx / 44, q = idx - row * 44;
    const int c0 = q * 8;
    short8 o;
    if (c0 <= 312) {                       // c0+7 <= 319 < 322: all valid
      const float* src = inputs + (size_t)row * 322 + c0;
      const f32x4u a = *(const f32x4u*)src;
      const f32x4u bvv = *(const f32x4u*)(src + 4);
#pragma unroll
      for (int e = 0; e < 4; ++e) { o[e] = f2bf(a[e]); o[4 + e] = f2bf(bvv[e]); }
    } else if (c0 == 320) {                // 320,321 valid, rest pad
      const float* src = inputs + (size_t)row * 322 + 320;
      o = (short8)0;
      o[0] = f2bf(src[0]); o[1] = f2bf(src[1]);
    } else {
      o = (short8)0;
    }
    *(short8*)(xin + (size_t)row * 352 + c0) = o;
    return;
  }
  idx -= ROWS * 44;
  // ---- HID 8-wide: 256/row, fully aligned ----
  if (idx < ROWS * 32) {
    const float* src = hidden + (size_t)idx * 8;
    const f32x4 a = *(const f32x4*)src;
    const f32x4 bvv = *(const f32x4*)(src + 4);
    short8 o;
#pragma unroll
    for (int e = 0; e < 4; ++e) { o[e] = f2bf(a[e]); o[4 + e] = f2bf(bvv[e]); }
    *(short8*)(hid + (size_t)idx * 8) = o;
    return;
  }
  idx -= ROWS * 32;
  // ---- WIH 8-wide (768x256 = 196608 el = 24576 chunks) ----
  if (idx < 24576) {
    const float* src = Wih + (size_t)idx * 8;
    const f32x4 a = *(const f32x4*)src;
    const f32x4 bvv = *(const f32x4*)(src + 4);
    short8 o;
#pragma unroll
    for (int e = 0; e < 4; ++e) { o[e] = f2bf(a[e]); o[4 + e] = f2bf(bvv[e]); }
    *(short8*)(wihw + (size_t)idx * 8) = o;
    return;
  }
  idx -= 24576;
  // ---- WHH 8-wide ----
  if (idx < 24576) {
    const float* src = Whh + (size_t)idx * 8;
    const f32x4 a = *(const f32x4*)src;
    const f32x4 bvv = *(const f32x4*)(src + 4);
    short8 o;
#pragma unroll
    for (int e = 0; e < 4; ++e) { o[e] = f2bf(a[e]); o[4 + e] = f2bf(bvv[e]); }
    *(short8*)(whhw + (size_t)idx * 8) = o;
    return;
  }
  idx -= 24576;
  // ---- scalar small regions ----
  if (idx < 90112) {
    int r = idx / 352, c = idx - r * 352;
    w1w[idx] = (c < 322) ? f2bf(W1[r * 322 + c]) : (short)0;
    return;
  }
  idx -= 90112;
  if (idx < 32768) {
    wp2w[idx] = (idx < 33 * 256) ? f2bf(Wp2[idx]) : (short)0;
    return;
  }
  idx -= 32768;
  if (idx < 131072) {           // WPQK 512x256: [Wp1; Wq; Wk_h; 0]
    int r = idx >> 8, c = idx & 255;
    short v = 0;
    if (r < 256) v = f2bf(Wp1[r * 256 + c]);
    else if (r < 320) v = f2bf(Wq[(r - 256) * 256 + c]);
    else if (r < 384) v = f2bf(Wk[(size_t)(r - 320) * 261 + c]);
    wpqk[idx] = v;
    return;
  }
  idx -= 131072;
  if (idx < 147456) {           // [Wg1 ; Wd1] : 512x288
    wgdw[idx] = (idx < 73728) ? f2bf(Wg1[idx]) : f2bf(Wd1[idx - 73728]);
    return;
  }
  idx -= 147456;
  if (idx < 65536) {            // WFW 128x512: r0 = [Wg2|0]; r1..27 = [0|Wd2]
    int r = idx >> 9, c = idx & 511;
    short v = 0;
    if (r == 0 && c < 256) v = f2bf(Wg2[c]);
    else if (r >= 1 && r < 28 && c >= 256) v = f2bf(Wd2[(r - 1) * 256 + (c - 256)]);
    wfw[idx] = v;
    return;
  }
  idx -= 65536;
  if (idx < 384) {
    bpqkb[idx] = (idx < 256) ? bp1[idx] : ((idx < 320) ? bq[idx - 256] : 0.f);
    return;
  }
  idx -= 384;
  if (idx < 512) { bgd[idx] = (idx < 256) ? bg1[idx] : bd1[idx - 256]; return; }
  idx -= 512;
  if (idx < 128)
    bf2v[idx] = (idx == 0) ? bg2[0] : ((idx < 28) ? bd2[idx - 1] : 0.f);
}

// ---------------------------------------------------------------------------
// GRU elementwise.
// ---------------------------------------------------------------------------
__global__ __launch_bounds__(256) void gru_kernel(
    const short* __restrict__ GI, const short* __restrict__ GH,
    const float* __restrict__ Hin, float* __restrict__ H,
    short* __restrict__ FUS) {
  int idx = blockIdx.x * 256 + threadIdx.x;
  int row = idx >> 6;
  int c = (idx & 63) * 4;
  const short4v gr = *(const short4v*)(GI + (size_t)row * 768 + c);
  const short4v gz = *(const short4v*)(GI + (size_t)row * 768 + 256 + c);
  const short4v gn = *(const short4v*)(GI + (size_t)row * 768 + 512 + c);
  const short4v hr = *(const short4v*)(GH + (size_t)row * 768 + c);
  const short4v hz = *(const short4v*)(GH + (size_t)row * 768 + 256 + c);
  const short4v hn = *(const short4v*)(GH + (size_t)row * 768 + 512 + c);
  const f32x4 hi = *(const f32x4*)(Hin + (size_t)row * 256 + c);
  f32x4 o;
  short4v ob;
#pragma unroll
  for (int p = 0; p < 4; ++p) {
    float r = sigmoidf_(bf2f(gr[p]) + bf2f(hr[p]));
    float z = sigmoidf_(bf2f(gz[p]) + bf2f(hz[p]));
    float n = tanhf(bf2f(gn[p]) + r * bf2f(hn[p]));
    float h = (1.f - z) * n + z * hi[p];
    o[p] = h;
    ob[p] = f2bf(h);
  }
  *(f32x4*)(H + (size_t)row * 256 + c) = o;
  *(short4v*)(FUS + (size_t)row * 288 + c) = ob;
}

// ---------------------------------------------------------------------------
// Attention v11 (r20): attn8 + TWO b's per block (grid (512,4)).
// b-independent stages (wkr/bk/nk/ln) once; sv_s/q_s/kh-regs restaged per-b
// with a __syncthreads at loop entry (all waves must finish reading the
// previous b's sv_s). Halves block count -> better ramp/drain amortization;
// per-wave structure unchanged (r3 lesson: don't cut wave-level TLP).
// ---------------------------------------------------------------------------
__global__ __launch_bounds__(256) void attn9_kernel(
    const float* __restrict__ QK, const float* __restrict__ rel,
    const float* __restrict__ Wk, const float* __restrict__ bk,
    const float* __restrict__ SV, const float* __restrict__ null_key,
    const float* __restrict__ null_value, const float* __restrict__ ln_g,
    const float* __restrict__ ln_b, short* __restrict__ FUS) {
  const int y = blockIdx.y;             // 0..3
  const int t = threadIdx.x;
  const int wave = t >> 6, lane = t & 63;
  const int iA = y * 4 + wave;          // 0..15, always valid
  const int iB = iA + 16;               // 16..31; valid iff < 27
  const int bBv = (iB < 27);
  const int iBw = bBv ? iB : 26;
  const int h = lane & 3;
  const int j0 = lane >> 2;
  const int j1 = j0 + 16;
  const int j1r = (j1 < 27) ? j1 : 26;  // clamp for safe loads

  __shared__ float sv_s[28 * 32];       // rows 0..26 = SV, row 27 = null_value
  __shared__ float wkr_s[320];
  __shared__ float bk_s[64], nk_s[64];
  __shared__ float lng_s[32], lnb_s[32];
  __shared__ float q_s[4][2][64];
  __shared__ float qws_s[4][2][28];
  __shared__ float s_row[4][2][112];

  // ---- b-independent stage (once) ----
  for (int idx = t; idx < 320; idx += 256) {
    int a = idx / 5, r = idx - a * 5;
    wkr_s[idx] = Wk[(size_t)a * 261 + 256 + r];
  }
  if (t < 64) bk_s[t] = bk[t];
  else if (t < 128) nk_s[t - 64] = null_key[t - 64];
  else if (t < 160) sv_s[27 * 32 + (t - 128)] = null_value[t - 128];
  else if (t < 192) { lng_s[t - 160] = ln_g[t - 160]; lnb_s[t - 160] = ln_b[t - 160]; }

  for (int bb = 0; bb < 2; ++bb) {
    const int b = blockIdx.x * 2 + bb;
    if (bb) __syncthreads();            // all waves done reading previous sv_s

    // ---- per-b stage ----
    for (int idx = t; idx < 27 * 32; idx += 256)
      sv_s[idx] = SV[(size_t)b * 864 + idx];
    q_s[wave][0][lane] = QK[(size_t)(b * 27 + iA) * 128 + lane];
    q_s[wave][1][lane] = QK[(size_t)(b * 27 + iBw) * 128 + lane];
    __syncthreads();

    // ---- kh registers ----
    f32x4 kv0[4], kv1[4];
    {
      const float* khp0 = QK + (size_t)(b * 27 + j0) * 128 + 64 + h * 16;
      const float* khp1 = QK + (size_t)(b * 27 + j1r) * 128 + 64 + h * 16;
#pragma unroll
      for (int c = 0; c < 4; ++c) kv0[c] = *(const f32x4*)(khp0 + c * 4);
#pragma unroll
      for (int c = 0; c < 4; ++c) kv1[c] = *(const f32x4*)(khp1 + c * 4);
    }

    // ---- qws BOTH rows: lanes 0..27 row A, lanes 32..59 row B ----
    {
      const int s = lane >> 5;
      const int ls = lane & 31;
      if (ls < 28) {
        float acc = 0.f;
        const float* q = q_s[wave][s];
        if (ls < 20) {
          const int qh = ls / 5, r = ls - qh * 5;
#pragma unroll
          for (int d = 0; d < 16; ++d)
            acc += q[qh * 16 + d] * wkr_s[(qh * 16 + d) * 5 + r];
        } else if (ls < 24) {
          const int qh = ls - 20;
#pragma unroll
          for (int d = 0; d < 16; ++d)
            acc += q[qh * 16 + d] * bk_s[qh * 16 + d];
        } else {
          const int qh = ls - 24;
#pragma unroll
          for (int d = 0; d < 16; ++d)
            acc += q[qh * 16 + d] * nk_s[qh * 16 + d];
        }
        qws_s[wave][s][ls] = acc;
      }
    }
    __builtin_amdgcn_wave_barrier();

    // ---- per-lane coefficients for h, both rows ----
    float qw[2][5], qbk[2], qnull[2];
    f32x4 qreg[2][4];
#pragma unroll
    for (int s = 0; s < 2; ++s) {
#pragma unroll
      for (int r = 0; r < 5; ++r) qw[s][r] = qws_s[wave][s][h * 5 + r];
      qbk[s]   = qws_s[wave][s][20 + h];
      qnull[s] = qws_s[wave][s][24 + h];
#pragma unroll
      for (int c = 0; c < 4; ++c)
        qreg[s][c] = *(const f32x4*)&q_s[wave][s][h * 16 + c * 4];
    }
    const float* relA = rel + (size_t)(b * 27 + iA) * 135;
    const float* relB = rel + (size_t)(b * 27 + iBw) * 135;

    // ---- scores: kh from registers, shared across both rows ----
#pragma unroll
    for (int s = 0; s < 2; ++s) {
      const int ii = s ? iB : iA;
      const float* rl = s ? relB : relA;
      float a0 = qbk[s];
#pragma unroll
      for (int c = 0; c < 4; ++c)
#pragma unroll
        for (int e = 0; e < 4; ++e) a0 += qreg[s][c][e] * kv0[c][e];
      {
        const float* rp = rl + j0 * 5;
        a0 += rp[0] * qw[s][0] + rp[1] * qw[s][1] + rp[2] * qw[s][2]
            + rp[3] * qw[s][3] + rp[4] * qw[s][4];
      }
      float sc0 = a0 * 0.25f;
      if (j0 == ii) sc0 = NEGV;
      s_row[wave][s][lane] = sc0;
      if (lane < 48) {                  // item lane+64 exists (j1 in 16..27)
        float sc1;
        if (j1 < 27) {
          float a1 = qbk[s];
#pragma unroll
          for (int c = 0; c < 4; ++c)
#pragma unroll
            for (int e = 0; e < 4; ++e) a1 += qreg[s][c][e] * kv1[c][e];
          const float* rp = rl + j1 * 5;
          a1 += rp[0] * qw[s][0] + rp[1] * qw[s][1] + rp[2] * qw[s][2]
              + rp[3] * qw[s][3] + rp[4] * qw[s][4];
          sc1 = a1 * 0.25f;
          if (j1 == ii) sc1 = NEGV;
        } else {
          sc1 = qnull[s] * 0.25f;       // j1 == 27: null column
        }
        s_row[wave][s][lane + 64] = sc1;
      }
    }
    __builtin_amdgcn_wave_barrier();

    // ---- top4 + masked softmax: both rows, interleaved shuffle chains ----
    {
      const int g = lane >> 4;
      const int li = lane & 15;
      const int jj1 = li + 16;
      float v0[2], v1[2], w0[2], w1[2], m0[2], thr[2];
#pragma unroll
      for (int s = 0; s < 2; ++s) {
        v0[s] = s_row[wave][s][li * 4 + g];
        v1[s] = (jj1 < 28) ? s_row[wave][s][jj1 * 4 + g] : -INFINITY;
        w0[s] = v0[s]; w1[s] = v1[s];
      }
#pragma unroll
      for (int r = 0; r < 4; ++r) {
        float gm[2];
#pragma unroll
        for (int s = 0; s < 2; ++s) gm[s] = fmaxf(w0[s], w1[s]);
#pragma unroll
        for (int off = 8; off; off >>= 1) {
#pragma unroll
          for (int s = 0; s < 2; ++s) gm[s] = fmaxf(gm[s], __shfl_xor(gm[s], off));
        }
#pragma unroll
        for (int s = 0; s < 2; ++s) {
          if (r == 0) m0[s] = gm[s];
          thr[s] = gm[s];
          const unsigned long long b0 = __ballot(w0[s] == gm[s]);
          const unsigned long long b1 = __ballot(w1[s] == gm[s]);
          const unsigned seg0 = (unsigned)(b0 >> (g * 16)) & 0xFFFFu;
          const unsigned seg1 = (unsigned)(b1 >> (g * 16)) & 0xFFFFu;
          if (seg0) { if (li == __builtin_ctz(seg0)) w0[s] = -INFINITY; }
          else      { if (li == __builtin_ctz(seg1)) w1[s] = -INFINITY; }
        }
      }
      float e0[2], e1[2], inv[2];
#pragma unroll
      for (int s = 0; s < 2; ++s) {
        e0[s] = (v0[s] >= thr[s]) ? __expf(v0[s] - m0[s]) : 0.f;
        e1[s] = (jj1 < 28 && v1[s] >= thr[s]) ? __expf(v1[s] - m0[s]) : 0.f;
      }
      float ssum[2];
#pragma unroll
      for (int s = 0; s < 2; ++s) ssum[s] = e0[s] + e1[s];
#pragma unroll
      for (int off = 8; off; off >>= 1) {
#pragma unroll
        for (int s = 0; s < 2; ++s) ssum[s] += __shfl_xor(ssum[s], off);
      }
#pragma unroll
      for (int s = 0; s < 2; ++s) {
        inv[s] = 1.f / ssum[s];
        s_row[wave][s][li * 4 + g] = e0[s] * inv[s];
        if (jj1 < 28) s_row[wave][s][jj1 * 4 + g] = e1[s] * inv[s];
      }
    }
    __builtin_amdgcn_wave_barrier();

    // ---- messages + layernorm: both rows; sv_s loaded once per j ----
    {
      const int sl = lane & 31;
      const int mh = sl >> 3;
      const int jbase = (lane >> 5) * 14;  // half0: j 0..13, half1: j 14..27
      float acc[2] = {0.f, 0.f};
#pragma unroll
      for (int jj = 0; jj < 14; ++jj) {
        const int j = jbase + jj;
        const float svv = sv_s[j * 32 + sl];          // row 27 = null_value
        acc[0] += s_row[wave][0][j * 4 + mh] * svv;
        acc[1] += s_row[wave][1][j * 4 + mh] * svv;
      }
#pragma unroll
      for (int s = 0; s < 2; ++s) acc[s] += __shfl_xor(acc[s], 32);
      float sum[2] = {acc[0], acc[1]};
#pragma unroll
      for (int off = 16; off; off >>= 1) {
#pragma unroll
        for (int s = 0; s < 2; ++s) sum[s] += __shfl_xor(sum[s], off);
      }
      float d[2], sq[2];
#pragma unroll
      for (int s = 0; s < 2; ++s) { d[s] = acc[s] - sum[s] * (1.f / 32.f); sq[s] = d[s] * d[s]; }
#pragma unroll
      for (int off = 16; off; off >>= 1) {
#pragma unroll
        for (int s = 0; s < 2; ++s) sq[s] += __shfl_xor(sq[s], off);
      }
      if (lane < 32) {
        const float nvA = d[0] * rsqrtf(sq[0] * (1.f / 32.f) + 1e-5f) * lng_s[sl] + lnb_s[sl];
        FUS[(size_t)(b * 27 + iA) * 288 + 256 + sl] = f2bf(nvA);
        if (bBv) {
          const float nvB = d[1] * rsqrtf(sq[1] * (1.f / 32.f) + 1e-5f) * lng_s[sl] + lnb_s[sl];
          FUS[(size_t)(b * 27 + iB) * 288 + 256 + sl] = f2bf(nvB);
        }
      }
    }
    __builtin_amdgcn_wave_barrier();
  }
}

// ---------------------------------------------------------------------------
extern "C" void kernel_launch(void* const* d_in, const int* in_sizes, int n_in,
                              void* d_out, int out_size, void* d_ws, size_t ws_size,
                              hipStream_t stream) {
  const float* inputs = (const float*)d_in[0];
  const float* hidden = (const float*)d_in[1];
  const float* rel    = (const float*)d_in[2];
  const float* W1  = (const float*)d_in[3];  const float* b1  = (const float*)d_in[4];
  const float* Wih = (const float*)d_in[5];  const float* bih = (const float*)d_in[6];
  const float* Whh = (const float*)d_in[7];  const float* bhh = (const float*)d_in[8];
  const float* Wp1 = (const float*)d_in[9];  const float* bp1 = (const float*)d_in[10];
  const float* Wp2 = (const float*)d_in[11]; const float* bp2 = (const float*)d_in[12];
  const float* Wq  = (const float*)d_in[13]; const float* bq  = (const float*)d_in[14];
  const float* Wk  = (const float*)d_in[15]; const float* bk  = (const float*)d_in[16];
  const float* Wv  = (const float*)d_in[17]; const float* bv  = (const float*)d_in[18];
  const float* ln_g = (const float*)d_in[19]; const float* ln_b = (const float*)d_in[20];
  const float* Wg1 = (const float*)d_in[21]; const float* bg1 = (const float*)d_in[22];
  const float* Wg2 = (const float*)d_in[23]; const float* bg2 = (const float*)d_in[24];
  const float* Wd1 = (const float*)d_in[25]; const float* bd1 = (const float*)d_in[26];
  const float* Wd2 = (const float*)d_in[27]; const float* bd2 = (const float*)d_in[28];
  const float* null_key   = (const float*)d_in[29];
  const float* null_value = (const float*)d_in[30];

  // ---- workspace layout (time-multiplexed; overlap-audited r7) ----
  char* wsb = (char*)d_ws;
  short* GIB = (short*)(wsb + 0);                    // 27648x768 bf16 (42.5MB)
  short* GDB = (short*)(wsb + 0);                    // 27648x512 bf16 (28.3MB)
  short* XINB = (short*)(wsb + 42467328);            // 27648x352 bf16
  short* GHB  = (short*)(wsb + 42467328);            // 27648x768 bf16 (all of R1)
  float* LOG  = (float*)(wsb + 42467328);            // +0       : 3.65MB
  float* QKB  = (float*)(wsb + 42467328 + 4194304);  // +4MiB    : 14.16MB -> ends +18.35MB
  float* SVB  = (float*)(wsb + 42467328 + 18874368); // +18MiB   : 3.54MB  -> ends +22.4MB
  short* XB   = (short*)(wsb + 84934656);
  short* FUS  = (short*)(wsb + 84934656);
  short* HIDB = (short*)(wsb + 84934656 + 16777216);
  short* P1B  = (short*)(wsb + 84934656 + 16777216);
  // Weights (persistent)
  char* wb = wsb + 115867648;
  short* W1W   = (short*)(wb + 0);        // 256x352
  short* WIHW  = (short*)(wb + 180224);   // 768x256
  short* WHHW  = (short*)(wb + 573440);   // 768x256
  short* WP2W  = (short*)(wb + 966656);   // 128x256
  short* WPQK  = (short*)(wb + 1032192);  // 512x256
  short* WGDW  = (short*)(wb + 1294336);  // 512x288
  short* WFW   = (short*)(wb + 1589248);  // 128x512
  float* BPQKb = (float*)(wb + 1720320);  // 384
  float* BGD   = (float*)(wb + 1721856);  // 512
  float* BF2   = (float*)(wb + 1723904);  // 128

  float* out = (float*)d_out;
  float* H   = out + (size_t)ROWS * 33;   // h output region, fp32

  // 1. bf16 conversions / packing (acts + weights, one launch; r15 8-wide)
  conv_all<<<10228, 256, 0, stream>>>(inputs, hidden,
                                      W1, Wih, Whh, Wp1, Wp2, Wq, Wk, Wg1, Wd1,
                                      Wg2, Wd2, bp1, bq, bg1, bd1, bg2, bd2,
                                      XINB, HIDB,
                                      W1W, WIHW, WHHW, WP2W, WPQK, WGDW, WFW,
                                      BPQKb, BGD, BF2);
  // 2. X = relu(inputs @ W1^T + b1)   K=352 -> 5x64 + 32 tail (48KB LDS)
  gemm_mfma<1, 1><<<dim3(216, 2), 256, 49152, stream>>>(XINB, 352, W1W, 352, b1, XB, 256, 256, 352);
  // 3. GI = X @ Wih^T + bih  AND  GH = hidden @ Whh^T + bhh (one dispatch)
  gemm_gigh<<<dim3(216, 12), 256, 32768, stream>>>(XB, HIDB, WIHW, WHHW, bih, bhh, GIB, GHB);
  // 4. GRU -> H (fp32, d_out) + fusion[:,0:256] (bf16)
  gru_kernel<<<6912, 256, 0, stream>>>(GIB, GHB, hidden, H, FUS);
  // 5. [P1 | QK] = h @ [Wp1; Wq; Wk_h]^T + [bp1; bq; 0]   K=256
  gemm_pqk<<<dim3(216, 3), 256, 32768, stream>>>(FUS, WPQK, BPQKb, P1B, QKB);
  // 6. logits GEMM + fused sender-values
  gemm_logits_sv<<<216, 256, 32768, stream>>>(P1B, WP2W, bp2, Wv, bv, LOG, SVB);
  // 7. attention v11 -> fusion[:,256:288]  (2 b per block)
  attn9_kernel<<<dim3(512, 4), 256, 0, stream>>>(QKB, rel, Wk, bk, SVB, null_key,
                                                 null_value, ln_g, ln_b, FUS);
  // 8. [G1 | D1] = relu(fusion @ [Wg1; Wd1]^T + [bg1; bd1])  K=288 -> 4x64+32
  gemm_mfma<1, 1><<<dim3(216, 4), 256, 49152, stream>>>(FUS, 288, WGDW, 288, BGD, GDB, 512, 512, 288);
  // 9. GDf GEMM + fused final fuse
  gemm_gdf_fuse<<<216, 256, 32768, stream>>>(GDB, WFW, BF2, LOG, out);
}

// Round 16
// 364.495 us; speedup vs baseline: 1.0560x; 1.0560x over previous
//
#include <hip/hip_runtime.h>
#include <cstdint>
#include <cstddef>

#define ROWS 27648
#define NEGV (-1e10f)

typedef __attribute__((ext_vector_type(8))) short bf16x8;
typedef __attribute__((ext_vector_type(8))) short short8;
typedef __attribute__((ext_vector_type(4))) short short4v;
typedef __attribute__((ext_vector_type(4))) float f32x4;
typedef __attribute__((ext_vector_type(4), aligned(4))) float f32x4u;  // 4B-aligned vector load

__device__ __forceinline__ float sigmoidf_(float x) { return 1.f / (1.f + __expf(-x)); }
__device__ __forceinline__ float bf2f(short s) {
  union { float f; unsigned u; } x; x.u = ((unsigned)(unsigned short)s) << 16; return x.f;
}
__device__ __forceinline__ short f2bf(float f) {   // RNE
  union { float f; unsigned u; } x; x.f = f;
  unsigned r = (x.u + 0x7fffu + ((x.u >> 16) & 1u)) >> 16;
  return (short)r;
}

// ---------------------------------------------------------------------------
// bf16 MFMA GEMM r11: BK=64, swizzled LDS (validated r5: -11us total).
// ---------------------------------------------------------------------------
#define GLDS(gp, lp) __builtin_amdgcn_global_load_lds( \
  (const __attribute__((address_space(1))) void*)(gp), \
  (__attribute__((address_space(3))) void*)(lp), 16, 0, 0)

template <int ACT, int BF16OUT>
__global__ __launch_bounds__(256) void gemm_mfma(
    const short* __restrict__ A, int lda,
    const short* __restrict__ B, int ldb,
    const float* __restrict__ bias,
    void* __restrict__ Cv, int ldc, int nstore, int K) {
  extern __shared__ short smem[];
  short* As = smem;              // [128][64] swizzled, 16 KB
  short* Bs = smem + 8192;       // [128][64] swizzled, 16 KB
  const int tid = threadIdx.x;
  const int wave = tid >> 6, lane = tid & 63;
  const int m0 = blockIdx.x * 128, n0 = blockIdx.y * 128;
  const int srow = lane >> 3;                    // 0..7 within 8-row GLDS group
  const int scol = ((lane & 7) ^ srow) * 8;      // swizzled 16B chunk (shorts)
  const int sr0 = wave * 32;
  const int wm = (wave >> 1) * 64, wn = (wave & 1) * 64;
  const int fr = lane & 15, fk = (lane >> 4) * 8;

  f32x4 acc[4][4] = {};

  const short* pA = A + (size_t)(m0 + sr0 + srow) * lda + scol;
  const short* pB = B + (size_t)(n0 + sr0 + srow) * ldb + scol;
  short* lA = &As[sr0 * 64];
  short* lB = &Bs[sr0 * 64];

  const int KB = K & ~63;
  for (int k0 = 0; k0 < KB; k0 += 64) {
#pragma unroll
    for (int g = 0; g < 4; ++g) {
      GLDS(pA + k0 + g * 8 * lda, lA + g * 512);
      GLDS(pB + k0 + g * 8 * ldb, lB + g * 512);
    }
    __syncthreads();
#pragma unroll
    for (int ks = 0; ks < 2; ++ks) {
      bf16x8 af[4], bfr[4];
#pragma unroll
      for (int t = 0; t < 4; ++t) {
        const int ra = wm + t * 16 + fr;
        const int rb = wn + t * 16 + fr;
        af[t]  = *(const bf16x8*)&As[(ra * 64 + ks * 32 + fk) ^ ((ra & 7) << 3)];
        bfr[t] = *(const bf16x8*)&Bs[(rb * 64 + ks * 32 + fk) ^ ((rb & 7) << 3)];
      }
#pragma unroll
      for (int i = 0; i < 4; ++i)
#pragma unroll
        for (int j = 0; j < 4; ++j)
          acc[i][j] = __builtin_amdgcn_mfma_f32_16x16x32_bf16(af[i], bfr[j], acc[i][j], 0, 0, 0);
    }
    __syncthreads();
  }

  if (K & 32) {                  // 32-wide tail: separate linear buffers
    short* As2 = smem + 16384;   // [128][32], 8 KB
    short* Bs2 = smem + 20480;   // [128][32], 8 KB
    const int sr2 = lane >> 2, sc2 = (lane & 3) * 8;
    const short* qA = A + (size_t)(m0 + sr0 + sr2) * lda + sc2 + KB;
    const short* qB = B + (size_t)(n0 + sr0 + sr2) * ldb + sc2 + KB;
    GLDS(qA, &As2[sr0 * 32]);
    GLDS(qA + 16 * lda, &As2[(sr0 + 16) * 32]);
    GLDS(qB, &Bs2[sr0 * 32]);
    GLDS(qB + 16 * ldb, &Bs2[(sr0 + 16) * 32]);
    __syncthreads();
    bf16x8 af[4], bfr[4];
#pragma unroll
    for (int t = 0; t < 4; ++t) {
      af[t]  = *(const bf16x8*)&As2[(wm + t * 16 + fr) * 32 + fk];
      bfr[t] = *(const bf16x8*)&Bs2[(wn + t * 16 + fr) * 32 + fk];
    }
#pragma unroll
    for (int i = 0; i < 4; ++i)
#pragma unroll
      for (int j = 0; j < 4; ++j)
        acc[i][j] = __builtin_amdgcn_mfma_f32_16x16x32_bf16(af[i], bfr[j], acc[i][j], 0, 0, 0);
  }

  const int rbase = m0 + wm + (lane >> 4) * 4;
#pragma unroll
  for (int j = 0; j < 4; ++j) {
    const int col = n0 + wn + j * 16 + fr;
    if (col >= nstore) continue;
    const float bv = bias ? bias[col] : 0.f;
#pragma unroll
    for (int i = 0; i < 4; ++i)
#pragma unroll
      for (int r = 0; r < 4; ++r) {
        const int row = rbase + i * 16 + r;
        float v = acc[i][j][r] + bv;
        if (ACT) v = fmaxf(v, 0.f);
        if (BF16OUT) ((short*)Cv)[(size_t)row * ldc + col] = f2bf(v);
        else         ((float*)Cv)[(size_t)row * ldc + col] = v;
      }
  }
}

// ---------------------------------------------------------------------------
// r19: GI and GH GEMMs merged in one dispatch (validated r14: -14us).
// blockIdx.y < 6 -> GI = X @ Wih^T + bih; else GH = hidden @ Whh^T + bhh.
// ---------------------------------------------------------------------------
__global__ __launch_bounds__(256) void gemm_gigh(
    const short* __restrict__ XB, const short* __restrict__ HIDB,
    const short* __restrict__ WIH, const short* __restrict__ WHH,
    const float* __restrict__ bih, const float* __restrict__ bhh,
    short* __restrict__ GI, short* __restrict__ GH) {
  extern __shared__ short smem[];
  short* As = smem;
  short* Bs = smem + 8192;
  const int tid = threadIdx.x;
  const int wave = tid >> 6, lane = tid & 63;
  const int half = (blockIdx.y >= 6);
  const int m0 = blockIdx.x * 128;
  const int n0 = (blockIdx.y - (half ? 6 : 0)) * 128;
  const short* A = half ? HIDB : XB;
  const short* B = half ? WHH : WIH;
  const float* bias = half ? bhh : bih;
  short* C = half ? GH : GI;
  const int srow = lane >> 3;
  const int scol = ((lane & 7) ^ srow) * 8;
  const int sr0 = wave * 32;
  const int wm = (wave >> 1) * 64, wn = (wave & 1) * 64;
  const int fr = lane & 15, fk = (lane >> 4) * 8;

  f32x4 acc[4][4] = {};
  const short* pA = A + (size_t)(m0 + sr0 + srow) * 256 + scol;
  const short* pB = B + (size_t)(n0 + sr0 + srow) * 256 + scol;
  short* lA = &As[sr0 * 64];
  short* lB = &Bs[sr0 * 64];

  for (int k0 = 0; k0 < 256; k0 += 64) {
#pragma unroll
    for (int g = 0; g < 4; ++g) {
      GLDS(pA + k0 + g * 8 * 256, lA + g * 512);
      GLDS(pB + k0 + g * 8 * 256, lB + g * 512);
    }
    __syncthreads();
#pragma unroll
    for (int ks = 0; ks < 2; ++ks) {
      bf16x8 af[4], bfr[4];
#pragma unroll
      for (int t = 0; t < 4; ++t) {
        const int ra = wm + t * 16 + fr;
        const int rb = wn + t * 16 + fr;
        af[t]  = *(const bf16x8*)&As[(ra * 64 + ks * 32 + fk) ^ ((ra & 7) << 3)];
        bfr[t] = *(const bf16x8*)&Bs[(rb * 64 + ks * 32 + fk) ^ ((rb & 7) << 3)];
      }
#pragma unroll
      for (int i = 0; i < 4; ++i)
#pragma unroll
        for (int j = 0; j < 4; ++j)
          acc[i][j] = __builtin_amdgcn_mfma_f32_16x16x32_bf16(af[i], bfr[j], acc[i][j], 0, 0, 0);
    }
    __syncthreads();
  }

  const int rbase = m0 + wm + (lane >> 4) * 4;
#pragma unroll
  for (int j = 0; j < 4; ++j) {
    const int col = n0 + wn + j * 16 + fr;
    const float bv = bias[col];
#pragma unroll
    for (int i = 0; i < 4; ++i)
#pragma unroll
      for (int r = 0; r < 4; ++r) {
        const int row = rbase + i * 16 + r;
        C[(size_t)row * 768 + col] = f2bf(acc[i][j][r] + bv);
      }
  }
}

// ---------------------------------------------------------------------------
// Split-output GEMM for [P1 | QK] (BK=64 swizzled, K=256, no tail).
// ---------------------------------------------------------------------------
__global__ __launch_bounds__(256) void gemm_pqk(
    const short* __restrict__ A, const short* __restrict__ B,
    const float* __restrict__ bias,
    short* __restrict__ P1, float* __restrict__ QK) {
  extern __shared__ short smem[];
  short* As = smem;
  short* Bs = smem + 8192;
  const int tid = threadIdx.x;
  const int wave = tid >> 6, lane = tid & 63;
  const int m0 = blockIdx.x * 128, n0 = blockIdx.y * 128;
  const int srow = lane >> 3;
  const int scol = ((lane & 7) ^ srow) * 8;
  const int sr0 = wave * 32;
  const int wm = (wave >> 1) * 64, wn = (wave & 1) * 64;
  const int fr = lane & 15, fk = (lane >> 4) * 8;

  f32x4 acc[4][4] = {};
  const short* pA = A + (size_t)(m0 + sr0 + srow) * 288 + scol;
  const short* pB = B + (size_t)(n0 + sr0 + srow) * 256 + scol;
  short* lA = &As[sr0 * 64];
  short* lB = &Bs[sr0 * 64];

  for (int k0 = 0; k0 < 256; k0 += 64) {
#pragma unroll
    for (int g = 0; g < 4; ++g) {
      GLDS(pA + k0 + g * 8 * 288, lA + g * 512);
      GLDS(pB + k0 + g * 8 * 256, lB + g * 512);
    }
    __syncthreads();
#pragma unroll
    for (int ks = 0; ks < 2; ++ks) {
      bf16x8 af[4], bfr[4];
#pragma unroll
      for (int t = 0; t < 4; ++t) {
        const int ra = wm + t * 16 + fr;
        const int rb = wn + t * 16 + fr;
        af[t]  = *(const bf16x8*)&As[(ra * 64 + ks * 32 + fk) ^ ((ra & 7) << 3)];
        bfr[t] = *(const bf16x8*)&Bs[(rb * 64 + ks * 32 + fk) ^ ((rb & 7) << 3)];
      }
#pragma unroll
      for (int i = 0; i < 4; ++i)
#pragma unroll
        for (int j = 0; j < 4; ++j)
          acc[i][j] = __builtin_amdgcn_mfma_f32_16x16x32_bf16(af[i], bfr[j], acc[i][j], 0, 0, 0);
    }
    __syncthreads();
  }

  const int rbase = m0 + wm + (lane >> 4) * 4;
#pragma unroll
  for (int j = 0; j < 4; ++j) {
    const int col = n0 + wn + j * 16 + fr;
    if (col >= 384) continue;
    const float bv = bias[col];
#pragma unroll
    for (int i = 0; i < 4; ++i)
#pragma unroll
      for (int r = 0; r < 4; ++r) {
        const int row = rbase + i * 16 + r;
        float v = acc[i][j][r] + bv;
        if (col < 256) {
          P1[(size_t)row * 256 + col] = f2bf(fmaxf(v, 0.f));
        } else {
          QK[(size_t)row * 128 + (col - 256)] = v;
        }
      }
  }
}

// ---------------------------------------------------------------------------
// r16: logits GEMM (K=256, N=33) + FUSED sv epilogue. Grid (216).
// ---------------------------------------------------------------------------
__global__ __launch_bounds__(256) void gemm_logits_sv(
    const short* __restrict__ A, const short* __restrict__ B,
    const float* __restrict__ bias,
    const float* __restrict__ Wv, const float* __restrict__ bv,
    float* __restrict__ LOG, float* __restrict__ SV) {
  extern __shared__ short smem[];
  short* As = smem;
  short* Bs = smem + 8192;
  const int tid = threadIdx.x;
  const int wave = tid >> 6, lane = tid & 63;
  const int m0 = blockIdx.x * 128;
  const int srow = lane >> 3;
  const int scol = ((lane & 7) ^ srow) * 8;
  const int sr0 = wave * 32;
  const int wm = (wave >> 1) * 64, wn = (wave & 1) * 64;
  const int fr = lane & 15, fk = (lane >> 4) * 8;

  f32x4 acc[4][4] = {};
  const short* pA = A + (size_t)(m0 + sr0 + srow) * 256 + scol;
  const short* pB = B + (size_t)(sr0 + srow) * 256 + scol;
  short* lA = &As[sr0 * 64];
  short* lB = &Bs[sr0 * 64];

  for (int k0 = 0; k0 < 256; k0 += 64) {
#pragma unroll
    for (int g = 0; g < 4; ++g) {
      GLDS(pA + k0 + g * 8 * 256, lA + g * 512);
      GLDS(pB + k0 + g * 8 * 256, lB + g * 512);
    }
    __syncthreads();
#pragma unroll
    for (int ks = 0; ks < 2; ++ks) {
      bf16x8 af[4], bfr[4];
#pragma unroll
      for (int t = 0; t < 4; ++t) {
        const int ra = wm + t * 16 + fr;
        const int rb = wn + t * 16 + fr;
        af[t]  = *(const bf16x8*)&As[(ra * 64 + ks * 32 + fk) ^ ((ra & 7) << 3)];
        bfr[t] = *(const bf16x8*)&Bs[(rb * 64 + ks * 32 + fk) ^ ((rb & 7) << 3)];
      }
#pragma unroll
      for (int i = 0; i < 4; ++i)
#pragma unroll
        for (int j = 0; j < 4; ++j)
          acc[i][j] = __builtin_amdgcn_mfma_f32_16x16x32_bf16(af[i], bfr[j], acc[i][j], 0, 0, 0);
    }
    __syncthreads();
  }

  // ---- epilogue: store LOG + stage tile in LDS (32KB free now) ----
  float* ls = (float*)smem;              // [128][33]
  const int rloc = wm + (lane >> 4) * 4; // local row base
  if (wn == 0) {
#pragma unroll
    for (int j = 0; j < 3; ++j) {
      const int col = j * 16 + fr;
      if (col < 33) {
        const float bvv = bias[col];
#pragma unroll
        for (int i = 0; i < 4; ++i)
#pragma unroll
          for (int r = 0; r < 4; ++r) {
            const int row = rloc + i * 16 + r;
            const float v = acc[i][j][r] + bvv;
            LOG[(size_t)(m0 + row) * 33 + col] = v;
            ls[row * 33 + col] = v;
          }
      }
    }
  }
  __syncthreads();

  // ---- sv: one thread per row ----
  if (tid < 128) {
    const float* base = &ls[tid * 33];
    float m = base[6];
#pragma unroll
    for (int c = 7; c < 33; ++c) m = fmaxf(m, base[c]);
    float p[27], s = 0.f;
#pragma unroll
    for (int c = 0; c < 27; ++c) { p[c] = __expf(base[6 + c] - m); s += p[c]; }
    const float inv = 1.f / s;
    float vs[29];
#pragma unroll
    for (int c = 0; c < 27; ++c) vs[c] = p[c] * inv;
    vs[27] = 1.f;
    vs[28] = inv;                        // top1 = max prob
    float* outp = SV + (size_t)(m0 + tid) * 32;
#pragma unroll
    for (int o4 = 0; o4 < 8; ++o4) {
      f32x4 ov;
#pragma unroll
      for (int e = 0; e < 4; ++e) {
        const int o = o4 * 4 + e;
        float acc2 = bv[o];
        const float* w = Wv + o * 29;
#pragma unroll
        for (int c = 0; c < 29; ++c) acc2 += w[c] * vs[c];
        ov[e] = acc2;
      }
      *(f32x4*)(outp + o4 * 4) = ov;
    }
  }
}

// ---------------------------------------------------------------------------
// r16: GDf GEMM (K=512, N=28) + FUSED final-fuse epilogue. Grid (216).
// ---------------------------------------------------------------------------
__global__ __launch_bounds__(256) void gemm_gdf_fuse(
    const short* __restrict__ A, const short* __restrict__ B,
    const float* __restrict__ bias,
    const float* __restrict__ LOG, float* __restrict__ out) {
  extern __shared__ short smem[];
  short* As = smem;
  short* Bs = smem + 8192;
  const int tid = threadIdx.x;
  const int wave = tid >> 6, lane = tid & 63;
  const int m0 = blockIdx.x * 128;
  const int srow = lane >> 3;
  const int scol = ((lane & 7) ^ srow) * 8;
  const int sr0 = wave * 32;
  const int wm = (wave >> 1) * 64, wn = (wave & 1) * 64;
  const int fr = lane & 15, fk = (lane >> 4) * 8;

  f32x4 acc[4][4] = {};
  const short* pA = A + (size_t)(m0 + sr0 + srow) * 512 + scol;
  const short* pB = B + (size_t)(sr0 + srow) * 512 + scol;
  short* lA = &As[sr0 * 64];
  short* lB = &Bs[sr0 * 64];

  for (int k0 = 0; k0 < 512; k0 += 64) {
#pragma unroll
    for (int g = 0; g < 4; ++g) {
      GLDS(pA + k0 + g * 8 * 512, lA + g * 512);
      GLDS(pB + k0 + g * 8 * 512, lB + g * 512);
    }
    __syncthreads();
#pragma unroll
    for (int ks = 0; ks < 2; ++ks) {
      bf16x8 af[4], bfr[4];
#pragma unroll
      for (int t = 0; t < 4; ++t) {
        const int ra = wm + t * 16 + fr;
        const int rb = wn + t * 16 + fr;
        af[t]  = *(const bf16x8*)&As[(ra * 64 + ks * 32 + fk) ^ ((ra & 7) << 3)];
        bfr[t] = *(const bf16x8*)&Bs[(rb * 64 + ks * 32 + fk) ^ ((rb & 7) << 3)];
      }
#pragma unroll
      for (int i = 0; i < 4; ++i)
#pragma unroll
        for (int j = 0; j < 4; ++j)
          acc[i][j] = __builtin_amdgcn_mfma_f32_16x16x32_bf16(af[i], bfr[j], acc[i][j], 0, 0, 0);
    }
    __syncthreads();
  }

  // ---- epilogue: stage GDf tile [128][28] in LDS ----
  float* ls = (float*)smem;
  const int rloc = wm + (lane >> 4) * 4;
  if (wn == 0) {
#pragma unroll
    for (int j = 0; j < 2; ++j) {
      const int col = j * 16 + fr;
      if (col < 28) {
        const float bvv = bias[col];
#pragma unroll
        for (int i = 0; i < 4; ++i)
#pragma unroll
          for (int r = 0; r < 4; ++r) {
            const int row = rloc + i * 16 + r;
            ls[row * 28 + col] = acc[i][j][r] + bvv;
          }
      }
    }
  }
  __syncthreads();

  // ---- fuse: out[row, 0..32] = LOG +/- 0.1 * gate * delta ----
  for (int idx = tid; idx < 128 * 33; idx += 256) {
    const int row = idx / 33;
    const int c = idx - row * 33;
    float v = LOG[(size_t)(m0 + row) * 33 + c];
    if (c >= 6) {
      const float gate = sigmoidf_(ls[row * 28]);
      v += 0.1f * gate * ls[row * 28 + (c - 5)];
    }
    out[(size_t)(m0 + row) * 33 + c] = v;
  }
}

// ---------------------------------------------------------------------------
// Combined activation + weight conversion r15: 8-wide vectorized big regions.
// ---------------------------------------------------------------------------
__global__ __launch_bounds__(256) void conv_all(
    const float* __restrict__ inputs, const float* __restrict__ hidden,
    const float* __restrict__ W1, const float* __restrict__ Wih,
    const float* __restrict__ Whh, const float* __restrict__ Wp1,
    const float* __restrict__ Wp2, const float* __restrict__ Wq,
    const float* __restrict__ Wk, const float* __restrict__ Wg1,
    const float* __restrict__ Wd1, const float* __restrict__ Wg2,
    const float* __restrict__ Wd2, const float* __restrict__ bp1,
    const float* __restrict__ bq, const float* __restrict__ bg1,
    const float* __restrict__ bd1, const float* __restrict__ bg2,
    const float* __restrict__ bd2,
    short* __restrict__ xin, short* __restrict__ hid,
    short* __restrict__ w1w, short* __restrict__ wihw, short* __restrict__ whhw,
    short* __restrict__ wp2w, short* __restrict__ wpqk, short* __restrict__ wgdw,
    short* __restrict__ wfw, float* __restrict__ bpqkb, float* __restrict__ bgd,
    float* __restrict__ bf2v) {
  int idx = blockIdx.x * 256 + threadIdx.x;
  // ---- XIN 8-wide: rows of 352 = 44 chunks; src row stride 322 (8B align) --
  if (idx < ROWS * 44) {
    const int row = idx / 44, q = idx - row * 44;
    const int c0 = q * 8;
    short8 o;
    if (c0 <= 312) {                       // c0+7 <= 319 < 322: all valid
      const float* src = inputs + (size_t)row * 322 + c0;
      const f32x4u a = *(const f32x4u*)src;
      const f32x4u bvv = *(const f32x4u*)(src + 4);
#pragma unroll
      for (int e = 0; e < 4; ++e) { o[e] = f2bf(a[e]); o[4 + e] = f2bf(bvv[e]); }
    } else if (c0 == 320) {                // 320,321 valid, rest pad
      const float* src = inputs + (size_t)row * 322 + 320;
      o = (short8)0;
      o[0] = f2bf(src[0]); o[1] = f2bf(src[1]);
    } else {
      o = (short8)0;
    }
    *(short8*)(xin + (size_t)row * 352 + c0) = o;
    return;
  }
  idx -= ROWS * 44;
  // ---- HID 8-wide: 256/row, fully aligned ----
  if (idx < ROWS * 32) {
    const float* src = hidden + (size_t)idx * 8;
    const f32x4 a = *(const f32x4*)src;
    const f32x4 bvv = *(const f32x4*)(src + 4);
    short8 o;
#pragma unroll
    for (int e = 0; e < 4; ++e) { o[e] = f2bf(a[e]); o[4 + e] = f2bf(bvv[e]); }
    *(short8*)(hid + (size_t)idx * 8) = o;
    return;
  }
  idx -= ROWS * 32;
  // ---- WIH 8-wide (768x256 = 196608 el = 24576 chunks) ----
  if (idx < 24576) {
    const float* src = Wih + (size_t)idx * 8;
    const f32x4 a = *(const f32x4*)src;
    const f32x4 bvv = *(const f32x4*)(src + 4);
    short8 o;
#pragma unroll
    for (int e = 0; e < 4; ++e) { o[e] = f2bf(a[e]); o[4 + e] = f2bf(bvv[e]); }
    *(short8*)(wihw + (size_t)idx * 8) = o;
    return;
  }
  idx -= 24576;
  // ---- WHH 8-wide ----
  if (idx < 24576) {
    const float* src = Whh + (size_t)idx * 8;
    const f32x4 a = *(const f32x4*)src;
    const f32x4 bvv = *(const f32x4*)(src + 4);
    short8 o;
#pragma unroll
    for (int e = 0; e < 4; ++e) { o[e] = f2bf(a[e]); o[4 + e] = f2bf(bvv[e]); }
    *(short8*)(whhw + (size_t)idx * 8) = o;
    return;
  }
  idx -= 24576;
  // ---- scalar small regions ----
  if (idx < 90112) {
    int r = idx / 352, c = idx - r * 352;
    w1w[idx] = (c < 322) ? f2bf(W1[r * 322 + c]) : (short)0;
    return;
  }
  idx -= 90112;
  if (idx < 32768) {
    wp2w[idx] = (idx < 33 * 256) ? f2bf(Wp2[idx]) : (short)0;
    return;
  }
  idx -= 32768;
  if (idx < 131072) {           // WPQK 512x256: [Wp1; Wq; Wk_h; 0]
    int r = idx >> 8, c = idx & 255;
    short v = 0;
    if (r < 256) v = f2bf(Wp1[r * 256 + c]);
    else if (r < 320) v = f2bf(Wq[(r - 256) * 256 + c]);
    else if (r < 384) v = f2bf(Wk[(size_t)(r - 320) * 261 + c]);
    wpqk[idx] = v;
    return;
  }
  idx -= 131072;
  if (idx < 147456) {           // [Wg1 ; Wd1] : 512x288
    wgdw[idx] = (idx < 73728) ? f2bf(Wg1[idx]) : f2bf(Wd1[idx - 73728]);
    return;
  }
  idx -= 147456;
  if (idx < 65536) {            // WFW 128x512: r0 = [Wg2|0]; r1..27 = [0|Wd2]
    int r = idx >> 9, c = idx & 511;
    short v = 0;
    if (r == 0 && c < 256) v = f2bf(Wg2[c]);
    else if (r >= 1 && r < 28 && c >= 256) v = f2bf(Wd2[(r - 1) * 256 + (c - 256)]);
    wfw[idx] = v;
    return;
  }
  idx -= 65536;
  if (idx < 384) {
    bpqkb[idx] = (idx < 256) ? bp1[idx] : ((idx < 320) ? bq[idx - 256] : 0.f);
    return;
  }
  idx -= 384;
  if (idx < 512) { bgd[idx] = (idx < 256) ? bg1[idx] : bd1[idx - 256]; return; }
  idx -= 512;
  if (idx < 128)
    bf2v[idx] = (idx == 0) ? bg2[0] : ((idx < 28) ? bd2[idx - 1] : 0.f);
}

// ---------------------------------------------------------------------------
// GRU elementwise.
// ---------------------------------------------------------------------------
__global__ __launch_bounds__(256) void gru_kernel(
    const short* __restrict__ GI, const short* __restrict__ GH,
    const float* __restrict__ Hin, float* __restrict__ H,
    short* __restrict__ FUS) {
  int idx = blockIdx.x * 256 + threadIdx.x;
  int row = idx >> 6;
  int c = (idx & 63) * 4;
  const short4v gr = *(const short4v*)(GI + (size_t)row * 768 + c);
  const short4v gz = *(const short4v*)(GI + (size_t)row * 768 + 256 + c);
  const short4v gn = *(const short4v*)(GI + (size_t)row * 768 + 512 + c);
  const short4v hr = *(const short4v*)(GH + (size_t)row * 768 + c);
  const short4v hz = *(const short4v*)(GH + (size_t)row * 768 + 256 + c);
  const short4v hn = *(const short4v*)(GH + (size_t)row * 768 + 512 + c);
  const f32x4 hi = *(const f32x4*)(Hin + (size_t)row * 256 + c);
  f32x4 o;
  short4v ob;
#pragma unroll
  for (int p = 0; p < 4; ++p) {
    float r = sigmoidf_(bf2f(gr[p]) + bf2f(hr[p]));
    float z = sigmoidf_(bf2f(gz[p]) + bf2f(hz[p]));
    float n = tanhf(bf2f(gn[p]) + r * bf2f(hn[p]));
    float h = (1.f - z) * n + z * hi[p];
    o[p] = h;
    ob[p] = f2bf(h);
  }
  *(f32x4*)(H + (size_t)row * 256 + c) = o;
  *(short4v*)(FUS + (size_t)row * 288 + c) = ob;
}

// ---------------------------------------------------------------------------
// Attention v10 (validated r13/r14: 43us, conflicts 786K, LDS 12.3KB).
// 2 rows/wave + kh in registers; grid (1024,4).
// ---------------------------------------------------------------------------
__global__ __launch_bounds__(256) void attn8_kernel(
    const float* __restrict__ QK, const float* __restrict__ rel,
    const float* __restrict__ Wk, const float* __restrict__ bk,
    const float* __restrict__ SV, const float* __restrict__ null_key,
    const float* __restrict__ null_value, const float* __restrict__ ln_g,
    const float* __restrict__ ln_b, short* __restrict__ FUS) {
  const int b = blockIdx.x;
  const int y = blockIdx.y;             // 0..3
  const int t = threadIdx.x;
  const int wave = t >> 6, lane = t & 63;
  const int iA = y * 4 + wave;          // 0..15, always valid
  const int iB = iA + 16;               // 16..31; valid iff < 27
  const int bBv = (iB < 27);
  const int iBw = bBv ? iB : 26;

  __shared__ float sv_s[28 * 32];       // rows 0..26 = SV, row 27 = null_value
  __shared__ float wkr_s[320];
  __shared__ float bk_s[64], nk_s[64];
  __shared__ float lng_s[32], lnb_s[32];
  __shared__ float q_s[4][2][64];
  __shared__ float qws_s[4][2][28];
  __shared__ float s_row[4][2][112];

  // ---- block stage ----
  for (int idx = t; idx < 27 * 32; idx += 256)
    sv_s[idx] = SV[(size_t)b * 864 + idx];
  for (int idx = t; idx < 320; idx += 256) {
    int a = idx / 5, r = idx - a * 5;
    wkr_s[idx] = Wk[(size_t)a * 261 + 256 + r];
  }
  if (t < 64) bk_s[t] = bk[t];
  else if (t < 128) nk_s[t - 64] = null_key[t - 64];
  else if (t < 160) sv_s[27 * 32 + (t - 128)] = null_value[t - 128];
  else if (t < 192) { lng_s[t - 160] = ln_g[t - 160]; lnb_s[t - 160] = ln_b[t - 160]; }
  q_s[wave][0][lane] = QK[(size_t)(b * 27 + iA) * 128 + lane];
  q_s[wave][1][lane] = QK[(size_t)(b * 27 + iBw) * 128 + lane];
  __syncthreads();

  // ---- kh registers: j0 = lane>>2 (0..15), j1 = j0+16 (16..31) ----
  const int h = lane & 3;
  const int j0 = lane >> 2;
  const int j1 = j0 + 16;
  const int j1r = (j1 < 27) ? j1 : 26;  // clamp for safe loads
  f32x4 kv0[4], kv1[4];
  {
    const float* khp0 = QK + (size_t)(b * 27 + j0) * 128 + 64 + h * 16;
    const float* khp1 = QK + (size_t)(b * 27 + j1r) * 128 + 64 + h * 16;
#pragma unroll
    for (int c = 0; c < 4; ++c) kv0[c] = *(const f32x4*)(khp0 + c * 4);
#pragma unroll
    for (int c = 0; c < 4; ++c) kv1[c] = *(const f32x4*)(khp1 + c * 4);
  }

  // ---- qws BOTH rows in one pass: lanes 0..27 row A, lanes 32..59 row B ----
  {
    const int s = lane >> 5;
    const int ls = lane & 31;
    if (ls < 28) {
      float acc = 0.f;
      const float* q = q_s[wave][s];
      if (ls < 20) {
        const int qh = ls / 5, r = ls - qh * 5;
#pragma unroll
        for (int d = 0; d < 16; ++d)
          acc += q[qh * 16 + d] * wkr_s[(qh * 16 + d) * 5 + r];
      } else if (ls < 24) {
        const int qh = ls - 20;
#pragma unroll
        for (int d = 0; d < 16; ++d)
          acc += q[qh * 16 + d] * bk_s[qh * 16 + d];
      } else {
        const int qh = ls - 24;
#pragma unroll
        for (int d = 0; d < 16; ++d)
          acc += q[qh * 16 + d] * nk_s[qh * 16 + d];
      }
      qws_s[wave][s][ls] = acc;
    }
  }
  __builtin_amdgcn_wave_barrier();

  // ---- per-lane coefficients for h = lane&3, both rows ----
  float qw[2][5], qbk[2], qnull[2];
  f32x4 qreg[2][4];
#pragma unroll
  for (int s = 0; s < 2; ++s) {
#pragma unroll
    for (int r = 0; r < 5; ++r) qw[s][r] = qws_s[wave][s][h * 5 + r];
    qbk[s]   = qws_s[wave][s][20 + h];
    qnull[s] = qws_s[wave][s][24 + h];
#pragma unroll
    for (int c = 0; c < 4; ++c)
      qreg[s][c] = *(const f32x4*)&q_s[wave][s][h * 16 + c * 4];
  }
  const float* relA = rel + (size_t)(b * 27 + iA) * 135;
  const float* relB = rel + (size_t)(b * 27 + iBw) * 135;

  // ---- scores: kh from registers, shared across both rows ----
#pragma unroll
  for (int s = 0; s < 2; ++s) {
    const int ii = s ? iB : iA;
    const float* rl = s ? relB : relA;
    float a0 = qbk[s];
#pragma unroll
    for (int c = 0; c < 4; ++c)
#pragma unroll
      for (int e = 0; e < 4; ++e) a0 += qreg[s][c][e] * kv0[c][e];
    {
      const float* rp = rl + j0 * 5;
      a0 += rp[0] * qw[s][0] + rp[1] * qw[s][1] + rp[2] * qw[s][2]
          + rp[3] * qw[s][3] + rp[4] * qw[s][4];
    }
    float sc0 = a0 * 0.25f;
    if (j0 == ii) sc0 = NEGV;
    s_row[wave][s][lane] = sc0;
    if (lane < 48) {                    // item lane+64 exists (j1 in 16..27)
      float sc1;
      if (j1 < 27) {
        float a1 = qbk[s];
#pragma unroll
        for (int c = 0; c < 4; ++c)
#pragma unroll
          for (int e = 0; e < 4; ++e) a1 += qreg[s][c][e] * kv1[c][e];
        const float* rp = rl + j1 * 5;
        a1 += rp[0] * qw[s][0] + rp[1] * qw[s][1] + rp[2] * qw[s][2]
            + rp[3] * qw[s][3] + rp[4] * qw[s][4];
        sc1 = a1 * 0.25f;
        if (j1 == ii) sc1 = NEGV;
      } else {
        sc1 = qnull[s] * 0.25f;         // j1 == 27: null column
      }
      s_row[wave][s][lane + 64] = sc1;
    }
  }
  __builtin_amdgcn_wave_barrier();

  // ---- top4 + masked softmax: both rows, interleaved shuffle chains ----
  {
    const int g = lane >> 4;
    const int li = lane & 15;
    const int jj1 = li + 16;
    float v0[2], v1[2], w0[2], w1[2], m0[2], thr[2];
#pragma unroll
    for (int s = 0; s < 2; ++s) {
      v0[s] = s_row[wave][s][li * 4 + g];
      v1[s] = (jj1 < 28) ? s_row[wave][s][jj1 * 4 + g] : -INFINITY;
      w0[s] = v0[s]; w1[s] = v1[s];
    }
#pragma unroll
    for (int r = 0; r < 4; ++r) {
      float gm[2];
#pragma unroll
      for (int s = 0; s < 2; ++s) gm[s] = fmaxf(w0[s], w1[s]);
#pragma unroll
      for (int off = 8; off; off >>= 1) {
#pragma unroll
        for (int s = 0; s < 2; ++s) gm[s] = fmaxf(gm[s], __shfl_xor(gm[s], off));
      }
#pragma unroll
      for (int s = 0; s < 2; ++s) {
        if (r == 0) m0[s] = gm[s];
        thr[s] = gm[s];
        const unsigned long long b0 = __ballot(w0[s] == gm[s]);
        const unsigned long long b1 = __ballot(w1[s] == gm[s]);
        const unsigned seg0 = (unsigned)(b0 >> (g * 16)) & 0xFFFFu;
        const unsigned seg1 = (unsigned)(b1 >> (g * 16)) & 0xFFFFu;
        if (seg0) { if (li == __builtin_ctz(seg0)) w0[s] = -INFINITY; }
        else      { if (li == __builtin_ctz(seg1)) w1[s] = -INFINITY; }
      }
    }
    float e0[2], e1[2], inv[2];
#pragma unroll
    for (int s = 0; s < 2; ++s) {
      e0[s] = (v0[s] >= thr[s]) ? __expf(v0[s] - m0[s]) : 0.f;
      e1[s] = (jj1 < 28 && v1[s] >= thr[s]) ? __expf(v1[s] - m0[s]) : 0.f;
    }
    float ssum[2];
#pragma unroll
    for (int s = 0; s < 2; ++s) ssum[s] = e0[s] + e1[s];
#pragma unroll
    for (int off = 8; off; off >>= 1) {
#pragma unroll
      for (int s = 0; s < 2; ++s) ssum[s] += __shfl_xor(ssum[s], off);
    }
#pragma unroll
    for (int s = 0; s < 2; ++s) {
      inv[s] = 1.f / ssum[s];
      s_row[wave][s][li * 4 + g] = e0[s] * inv[s];
      if (jj1 < 28) s_row[wave][s][jj1 * 4 + g] = e1[s] * inv[s];
    }
  }
  __builtin_amdgcn_wave_barrier();

  // ---- messages + layernorm: both rows; sv_s loaded once per j ----
  {
    const int sl = lane & 31;
    const int mh = sl >> 3;
    const int jbase = (lane >> 5) * 14;   // half0: j 0..13, half1: j 14..27
    float acc[2] = {0.f, 0.f};
#pragma unroll
    for (int jj = 0; jj < 14; ++jj) {
      const int j = jbase + jj;
      const float svv = sv_s[j * 32 + sl];          // row 27 = null_value
      acc[0] += s_row[wave][0][j * 4 + mh] * svv;
      acc[1] += s_row[wave][1][j * 4 + mh] * svv;
    }
#pragma unroll
    for (int s = 0; s < 2; ++s) acc[s] += __shfl_xor(acc[s], 32);
    float sum[2] = {acc[0], acc[1]};
#pragma unroll
    for (int off = 16; off; off >>= 1) {
#pragma unroll
      for (int s = 0; s < 2; ++s) sum[s] += __shfl_xor(sum[s], off);
    }
    float d[2], sq[2];
#pragma unroll
    for (int s = 0; s < 2; ++s) { d[s] = acc[s] - sum[s] * (1.f / 32.f); sq[s] = d[s] * d[s]; }
#pragma unroll
    for (int off = 16; off; off >>= 1) {
#pragma unroll
      for (int s = 0; s < 2; ++s) sq[s] += __shfl_xor(sq[s], off);
    }
    if (lane < 32) {
      const float nvA = d[0] * rsqrtf(sq[0] * (1.f / 32.f) + 1e-5f) * lng_s[sl] + lnb_s[sl];
      FUS[(size_t)(b * 27 + iA) * 288 + 256 + sl] = f2bf(nvA);
      if (bBv) {
        const float nvB = d[1] * rsqrtf(sq[1] * (1.f / 32.f) + 1e-5f) * lng_s[sl] + lnb_s[sl];
        FUS[(size_t)(b * 27 + iB) * 288 + 256 + sl] = f2bf(nvB);
      }
    }
  }
}

// ---------------------------------------------------------------------------
extern "C" void kernel_launch(void* const* d_in, const int* in_sizes, int n_in,
                              void* d_out, int out_size, void* d_ws, size_t ws_size,
                              hipStream_t stream) {
  const float* inputs = (const float*)d_in[0];
  const float* hidden = (const float*)d_in[1];
  const float* rel    = (const float*)d_in[2];
  const float* W1  = (const float*)d_in[3];  const float* b1  = (const float*)d_in[4];
  const float* Wih = (const float*)d_in[5];  const float* bih = (const float*)d_in[6];
  const float* Whh = (const float*)d_in[7];  const float* bhh = (const float*)d_in[8];
  const float* Wp1 = (const float*)d_in[9];  const float* bp1 = (const float*)d_in[10];
  const float* Wp2 = (const float*)d_in[11]; const float* bp2 = (const float*)d_in[12];
  const float* Wq  = (const float*)d_in[13]; const float* bq  = (const float*)d_in[14];
  const float* Wk  = (const float*)d_in[15]; const float* bk  = (const float*)d_in[16];
  const float* Wv  = (const float*)d_in[17]; const float* bv  = (const float*)d_in[18];
  const float* ln_g = (const float*)d_in[19]; const float* ln_b = (const float*)d_in[20];
  const float* Wg1 = (const float*)d_in[21]; const float* bg1 = (const float*)d_in[22];
  const float* Wg2 = (const float*)d_in[23]; const float* bg2 = (const float*)d_in[24];
  const float* Wd1 = (const float*)d_in[25]; const float* bd1 = (const float*)d_in[26];
  const float* Wd2 = (const float*)d_in[27]; const float* bd2 = (const float*)d_in[28];
  const float* null_key   = (const float*)d_in[29];
  const float* null_value = (const float*)d_in[30];

  // ---- workspace layout (time-multiplexed; overlap-audited r7) ----
  char* wsb = (char*)d_ws;
  short* GIB = (short*)(wsb + 0);                    // 27648x768 bf16 (42.5MB)
  short* GDB = (short*)(wsb + 0);                    // 27648x512 bf16 (28.3MB)
  short* XINB = (short*)(wsb + 42467328);            // 27648x352 bf16
  short* GHB  = (short*)(wsb + 42467328);            // 27648x768 bf16 (all of R1)
  float* LOG  = (float*)(wsb + 42467328);            // +0       : 3.65MB
  float* QKB  = (float*)(wsb + 42467328 + 4194304);  // +4MiB    : 14.16MB -> ends +18.35MB
  float* SVB  = (float*)(wsb + 42467328 + 18874368); // +18MiB   : 3.54MB  -> ends +22.4MB
  short* XB   = (short*)(wsb + 84934656);
  short* FUS  = (short*)(wsb + 84934656);
  short* HIDB = (short*)(wsb + 84934656 + 16777216);
  short* P1B  = (short*)(wsb + 84934656 + 16777216);
  // Weights (persistent)
  char* wb = wsb + 115867648;
  short* W1W   = (short*)(wb + 0);        // 256x352
  short* WIHW  = (short*)(wb + 180224);   // 768x256
  short* WHHW  = (short*)(wb + 573440);   // 768x256
  short* WP2W  = (short*)(wb + 966656);   // 128x256
  short* WPQK  = (short*)(wb + 1032192);  // 512x256
  short* WGDW  = (short*)(wb + 1294336);  // 512x288
  short* WFW   = (short*)(wb + 1589248);  // 128x512
  float* BPQKb = (float*)(wb + 1720320);  // 384
  float* BGD   = (float*)(wb + 1721856);  // 512
  float* BF2   = (float*)(wb + 1723904);  // 128

  float* out = (float*)d_out;
  float* H   = out + (size_t)ROWS * 33;   // h output region, fp32

  // 1. bf16 conversions / packing (acts + weights, one launch; r15 8-wide)
  conv_all<<<10228, 256, 0, stream>>>(inputs, hidden,
                                      W1, Wih, Whh, Wp1, Wp2, Wq, Wk, Wg1, Wd1,
                                      Wg2, Wd2, bp1, bq, bg1, bd1, bg2, bd2,
                                      XINB, HIDB,
                                      W1W, WIHW, WHHW, WP2W, WPQK, WGDW, WFW,
                                      BPQKb, BGD, BF2);
  // 2. X = relu(inputs @ W1^T + b1)   K=352 -> 5x64 + 32 tail (48KB LDS)
  gemm_mfma<1, 1><<<dim3(216, 2), 256, 49152, stream>>>(XINB, 352, W1W, 352, b1, XB, 256, 256, 352);
  // 3. GI = X @ Wih^T + bih  AND  GH = hidden @ Whh^T + bhh (one dispatch)
  gemm_gigh<<<dim3(216, 12), 256, 32768, stream>>>(XB, HIDB, WIHW, WHHW, bih, bhh, GIB, GHB);
  // 4. GRU -> H (fp32, d_out) + fusion[:,0:256] (bf16)
  gru_kernel<<<6912, 256, 0, stream>>>(GIB, GHB, hidden, H, FUS);
  // 5. [P1 | QK] = h @ [Wp1; Wq; Wk_h]^T + [bp1; bq; 0]   K=256
  gemm_pqk<<<dim3(216, 3), 256, 32768, stream>>>(FUS, WPQK, BPQKb, P1B, QKB);
  // 6. logits GEMM + fused sender-values
  gemm_logits_sv<<<216, 256, 32768, stream>>>(P1B, WP2W, bp2, Wv, bv, LOG, SVB);
  // 7. attention v10 -> fusion[:,256:288]
  attn8_kernel<<<dim3(1024, 4), 256, 0, stream>>>(QKB, rel, Wk, bk, SVB, null_key,
                                                  null_value, ln_g, ln_b, FUS);
  // 8. [G1 | D1] = relu(fusion @ [Wg1; Wd1]^T + [bg1; bd1])  K=288 -> 4x64+32
  gemm_mfma<1, 1><<<dim3(216, 4), 256, 49152, stream>>>(FUS, 288, WGDW, 288, BGD, GDB, 512, 512, 288);
  // 9. GDf GEMM + fused final fuse
  gemm_gdf_fuse<<<216, 256, 32768, stream>>>(GDB, WFW, BF2, LOG, out);
}

// Round 17
// 355.185 us; speedup vs baseline: 1.0837x; 1.0262x over previous
//
#include <hip/hip_runtime.h>
#include <cstdint>
#include <cstddef>

#define ROWS 27648
#define NEGV (-1e10f)

typedef __attribute__((ext_vector_type(8))) short bf16x8;
typedef __attribute__((ext_vector_type(8))) short short8;
typedef __attribute__((ext_vector_type(4))) short short4v;
typedef __attribute__((ext_vector_type(4))) float f32x4;
typedef __attribute__((ext_vector_type(4), aligned(4))) float f32x4u;  // 4B-aligned vector load

__device__ __forceinline__ float sigmoidf_(float x) { return 1.f / (1.f + __expf(-x)); }
__device__ __forceinline__ float bf2f(short s) {
  union { float f; unsigned u; } x; x.u = ((unsigned)(unsigned short)s) << 16; return x.f;
}
__device__ __forceinline__ short f2bf(float f) {   // RNE
  union { float f; unsigned u; } x; x.f = f;
  unsigned r = (x.u + 0x7fffu + ((x.u >> 16) & 1u)) >> 16;
  return (short)r;
}

// ---------------------------------------------------------------------------
// bf16 MFMA GEMM r11: BK=64, swizzled LDS (validated r5: -11us total).
// ---------------------------------------------------------------------------
#define GLDS(gp, lp) __builtin_amdgcn_global_load_lds( \
  (const __attribute__((address_space(1))) void*)(gp), \
  (__attribute__((address_space(3))) void*)(lp), 16, 0, 0)

template <int ACT, int BF16OUT>
__global__ __launch_bounds__(256) void gemm_mfma(
    const short* __restrict__ A, int lda,
    const short* __restrict__ B, int ldb,
    const float* __restrict__ bias,
    void* __restrict__ Cv, int ldc, int nstore, int K) {
  extern __shared__ short smem[];
  short* As = smem;              // [128][64] swizzled, 16 KB
  short* Bs = smem + 8192;       // [128][64] swizzled, 16 KB
  const int tid = threadIdx.x;
  const int wave = tid >> 6, lane = tid & 63;
  const int m0 = blockIdx.x * 128, n0 = blockIdx.y * 128;
  const int srow = lane >> 3;                    // 0..7 within 8-row GLDS group
  const int scol = ((lane & 7) ^ srow) * 8;      // swizzled 16B chunk (shorts)
  const int sr0 = wave * 32;
  const int wm = (wave >> 1) * 64, wn = (wave & 1) * 64;
  const int fr = lane & 15, fk = (lane >> 4) * 8;

  f32x4 acc[4][4] = {};

  const short* pA = A + (size_t)(m0 + sr0 + srow) * lda + scol;
  const short* pB = B + (size_t)(n0 + sr0 + srow) * ldb + scol;
  short* lA = &As[sr0 * 64];
  short* lB = &Bs[sr0 * 64];

  const int KB = K & ~63;
  for (int k0 = 0; k0 < KB; k0 += 64) {
#pragma unroll
    for (int g = 0; g < 4; ++g) {
      GLDS(pA + k0 + g * 8 * lda, lA + g * 512);
      GLDS(pB + k0 + g * 8 * ldb, lB + g * 512);
    }
    __syncthreads();
#pragma unroll
    for (int ks = 0; ks < 2; ++ks) {
      bf16x8 af[4], bfr[4];
#pragma unroll
      for (int t = 0; t < 4; ++t) {
        const int ra = wm + t * 16 + fr;
        const int rb = wn + t * 16 + fr;
        af[t]  = *(const bf16x8*)&As[(ra * 64 + ks * 32 + fk) ^ ((ra & 7) << 3)];
        bfr[t] = *(const bf16x8*)&Bs[(rb * 64 + ks * 32 + fk) ^ ((rb & 7) << 3)];
      }
#pragma unroll
      for (int i = 0; i < 4; ++i)
#pragma unroll
        for (int j = 0; j < 4; ++j)
          acc[i][j] = __builtin_amdgcn_mfma_f32_16x16x32_bf16(af[i], bfr[j], acc[i][j], 0, 0, 0);
    }
    __syncthreads();
  }

  if (K & 32) {                  // 32-wide tail: separate linear buffers
    short* As2 = smem + 16384;   // [128][32], 8 KB
    short* Bs2 = smem + 20480;   // [128][32], 8 KB
    const int sr2 = lane >> 2, sc2 = (lane & 3) * 8;
    const short* qA = A + (size_t)(m0 + sr0 + sr2) * lda + sc2 + KB;
    const short* qB = B + (size_t)(n0 + sr0 + sr2) * ldb + sc2 + KB;
    GLDS(qA, &As2[sr0 * 32]);
    GLDS(qA + 16 * lda, &As2[(sr0 + 16) * 32]);
    GLDS(qB, &Bs2[sr0 * 32]);
    GLDS(qB + 16 * ldb, &Bs2[(sr0 + 16) * 32]);
    __syncthreads();
    bf16x8 af[4], bfr[4];
#pragma unroll
    for (int t = 0; t < 4; ++t) {
      af[t]  = *(const bf16x8*)&As2[(wm + t * 16 + fr) * 32 + fk];
      bfr[t] = *(const bf16x8*)&Bs2[(wn + t * 16 + fr) * 32 + fk];
    }
#pragma unroll
    for (int i = 0; i < 4; ++i)
#pragma unroll
      for (int j = 0; j < 4; ++j)
        acc[i][j] = __builtin_amdgcn_mfma_f32_16x16x32_bf16(af[i], bfr[j], acc[i][j], 0, 0, 0);
  }

  const int rbase = m0 + wm + (lane >> 4) * 4;
#pragma unroll
  for (int j = 0; j < 4; ++j) {
    const int col = n0 + wn + j * 16 + fr;
    if (col >= nstore) continue;
    const float bv = bias ? bias[col] : 0.f;
#pragma unroll
    for (int i = 0; i < 4; ++i)
#pragma unroll
      for (int r = 0; r < 4; ++r) {
        const int row = rbase + i * 16 + r;
        float v = acc[i][j][r] + bv;
        if (ACT) v = fmaxf(v, 0.f);
        if (BF16OUT) ((short*)Cv)[(size_t)row * ldc + col] = f2bf(v);
        else         ((float*)Cv)[(size_t)row * ldc + col] = v;
      }
  }
}

// ---------------------------------------------------------------------------
// r22: GI/GH merged GEMM + LDS-staged COALESCED C-write.
// r16 counters: WRITE_SIZE 104MB vs 85MB ideal (32B store segments +
// write-allocate). Epilogue stages the 128x128 bf16 tile in the (dead) 32KB
// As/Bs LDS (XOR-swizzled at 16-short granularity, key (row>>2)&7 so the 4
// lane-groups hit disjoint banks), then stores 256B-contiguous short8 rows.
// ---------------------------------------------------------------------------
__global__ __launch_bounds__(256) void gemm_gigh(
    const short* __restrict__ XB, const short* __restrict__ HIDB,
    const short* __restrict__ WIH, const short* __restrict__ WHH,
    const float* __restrict__ bih, const float* __restrict__ bhh,
    short* __restrict__ GI, short* __restrict__ GH) {
  extern __shared__ short smem[];
  short* As = smem;
  short* Bs = smem + 8192;
  const int tid = threadIdx.x;
  const int wave = tid >> 6, lane = tid & 63;
  const int half = (blockIdx.y >= 6);
  const int m0 = blockIdx.x * 128;
  const int n0 = (blockIdx.y - (half ? 6 : 0)) * 128;
  const short* A = half ? HIDB : XB;
  const short* B = half ? WHH : WIH;
  const float* bias = half ? bhh : bih;
  short* C = half ? GH : GI;
  const int srow = lane >> 3;
  const int scol = ((lane & 7) ^ srow) * 8;
  const int sr0 = wave * 32;
  const int wm = (wave >> 1) * 64, wn = (wave & 1) * 64;
  const int fr = lane & 15, fk = (lane >> 4) * 8;

  f32x4 acc[4][4] = {};
  const short* pA = A + (size_t)(m0 + sr0 + srow) * 256 + scol;
  const short* pB = B + (size_t)(n0 + sr0 + srow) * 256 + scol;
  short* lA = &As[sr0 * 64];
  short* lB = &Bs[sr0 * 64];

  for (int k0 = 0; k0 < 256; k0 += 64) {
#pragma unroll
    for (int g = 0; g < 4; ++g) {
      GLDS(pA + k0 + g * 8 * 256, lA + g * 512);
      GLDS(pB + k0 + g * 8 * 256, lB + g * 512);
    }
    __syncthreads();
#pragma unroll
    for (int ks = 0; ks < 2; ++ks) {
      bf16x8 af[4], bfr[4];
#pragma unroll
      for (int t = 0; t < 4; ++t) {
        const int ra = wm + t * 16 + fr;
        const int rb = wn + t * 16 + fr;
        af[t]  = *(const bf16x8*)&As[(ra * 64 + ks * 32 + fk) ^ ((ra & 7) << 3)];
        bfr[t] = *(const bf16x8*)&Bs[(rb * 64 + ks * 32 + fk) ^ ((rb & 7) << 3)];
      }
#pragma unroll
      for (int i = 0; i < 4; ++i)
#pragma unroll
        for (int j = 0; j < 4; ++j)
          acc[i][j] = __builtin_amdgcn_mfma_f32_16x16x32_bf16(af[i], bfr[j], acc[i][j], 0, 0, 0);
    }
    __syncthreads();
  }

  // ---- epilogue: stage C tile in LDS (As/Bs dead, 32KB exactly) ----
  short* cs = smem;                      // [128][128] shorts, 16-short-chunk swz
  const int rl0 = wm + (lane >> 4) * 4;  // local row base
#pragma unroll
  for (int j = 0; j < 4; ++j) {
    const int cl = wn + j * 16 + fr;     // local col 0..127
    const float bv = bias[n0 + cl];
#pragma unroll
    for (int i = 0; i < 4; ++i)
#pragma unroll
      for (int r = 0; r < 4; ++r) {
        const int rowl = rl0 + i * 16 + r;
        const int lcol = (((cl >> 4) ^ ((rowl >> 2) & 7)) << 4) + (cl & 15);
        cs[rowl * 128 + lcol] = f2bf(acc[i][j][r] + bv);
      }
  }
  __syncthreads();

  // ---- coalesced store: 128 rows x 16 chunks of 8 shorts (256B/row) ----
  for (int idx = tid; idx < 128 * 16; idx += 256) {
    const int rowl = idx >> 4;
    const int ch = idx & 15;             // 8-short output chunk
    const int lcol = (((ch >> 1) ^ ((rowl >> 2) & 7)) << 4) + ((ch & 1) << 3);
    const short8 v = *(const short8*)&cs[rowl * 128 + lcol];
    *(short8*)&C[(size_t)(m0 + rowl) * 768 + n0 + ch * 8] = v;
  }
}

// ---------------------------------------------------------------------------
// Split-output GEMM for [P1 | QK] (BK=64 swizzled, K=256, no tail).
// ---------------------------------------------------------------------------
__global__ __launch_bounds__(256) void gemm_pqk(
    const short* __restrict__ A, const short* __restrict__ B,
    const float* __restrict__ bias,
    short* __restrict__ P1, float* __restrict__ QK) {
  extern __shared__ short smem[];
  short* As = smem;
  short* Bs = smem + 8192;
  const int tid = threadIdx.x;
  const int wave = tid >> 6, lane = tid & 63;
  const int m0 = blockIdx.x * 128, n0 = blockIdx.y * 128;
  const int srow = lane >> 3;
  const int scol = ((lane & 7) ^ srow) * 8;
  const int sr0 = wave * 32;
  const int wm = (wave >> 1) * 64, wn = (wave & 1) * 64;
  const int fr = lane & 15, fk = (lane >> 4) * 8;

  f32x4 acc[4][4] = {};
  const short* pA = A + (size_t)(m0 + sr0 + srow) * 288 + scol;
  const short* pB = B + (size_t)(n0 + sr0 + srow) * 256 + scol;
  short* lA = &As[sr0 * 64];
  short* lB = &Bs[sr0 * 64];

  for (int k0 = 0; k0 < 256; k0 += 64) {
#pragma unroll
    for (int g = 0; g < 4; ++g) {
      GLDS(pA + k0 + g * 8 * 288, lA + g * 512);
      GLDS(pB + k0 + g * 8 * 256, lB + g * 512);
    }
    __syncthreads();
#pragma unroll
    for (int ks = 0; ks < 2; ++ks) {
      bf16x8 af[4], bfr[4];
#pragma unroll
      for (int t = 0; t < 4; ++t) {
        const int ra = wm + t * 16 + fr;
        const int rb = wn + t * 16 + fr;
        af[t]  = *(const bf16x8*)&As[(ra * 64 + ks * 32 + fk) ^ ((ra & 7) << 3)];
        bfr[t] = *(const bf16x8*)&Bs[(rb * 64 + ks * 32 + fk) ^ ((rb & 7) << 3)];
      }
#pragma unroll
      for (int i = 0; i < 4; ++i)
#pragma unroll
        for (int j = 0; j < 4; ++j)
          acc[i][j] = __builtin_amdgcn_mfma_f32_16x16x32_bf16(af[i], bfr[j], acc[i][j], 0, 0, 0);
    }
    __syncthreads();
  }

  const int rbase = m0 + wm + (lane >> 4) * 4;
#pragma unroll
  for (int j = 0; j < 4; ++j) {
    const int col = n0 + wn + j * 16 + fr;
    if (col >= 384) continue;
    const float bv = bias[col];
#pragma unroll
    for (int i = 0; i < 4; ++i)
#pragma unroll
      for (int r = 0; r < 4; ++r) {
        const int row = rbase + i * 16 + r;
        float v = acc[i][j][r] + bv;
        if (col < 256) {
          P1[(size_t)row * 256 + col] = f2bf(fmaxf(v, 0.f));
        } else {
          QK[(size_t)row * 128 + (col - 256)] = v;
        }
      }
  }
}

// ---------------------------------------------------------------------------
// r16: logits GEMM (K=256, N=33) + FUSED sv epilogue. Grid (216).
// ---------------------------------------------------------------------------
__global__ __launch_bounds__(256) void gemm_logits_sv(
    const short* __restrict__ A, const short* __restrict__ B,
    const float* __restrict__ bias,
    const float* __restrict__ Wv, const float* __restrict__ bv,
    float* __restrict__ LOG, float* __restrict__ SV) {
  extern __shared__ short smem[];
  short* As = smem;
  short* Bs = smem + 8192;
  const int tid = threadIdx.x;
  const int wave = tid >> 6, lane = tid & 63;
  const int m0 = blockIdx.x * 128;
  const int srow = lane >> 3;
  const int scol = ((lane & 7) ^ srow) * 8;
  const int sr0 = wave * 32;
  const int wm = (wave >> 1) * 64, wn = (wave & 1) * 64;
  const int fr = lane & 15, fk = (lane >> 4) * 8;

  f32x4 acc[4][4] = {};
  const short* pA = A + (size_t)(m0 + sr0 + srow) * 256 + scol;
  const short* pB = B + (size_t)(sr0 + srow) * 256 + scol;
  short* lA = &As[sr0 * 64];
  short* lB = &Bs[sr0 * 64];

  for (int k0 = 0; k0 < 256; k0 += 64) {
#pragma unroll
    for (int g = 0; g < 4; ++g) {
      GLDS(pA + k0 + g * 8 * 256, lA + g * 512);
      GLDS(pB + k0 + g * 8 * 256, lB + g * 512);
    }
    __syncthreads();
#pragma unroll
    for (int ks = 0; ks < 2; ++ks) {
      bf16x8 af[4], bfr[4];
#pragma unroll
      for (int t = 0; t < 4; ++t) {
        const int ra = wm + t * 16 + fr;
        const int rb = wn + t * 16 + fr;
        af[t]  = *(const bf16x8*)&As[(ra * 64 + ks * 32 + fk) ^ ((ra & 7) << 3)];
        bfr[t] = *(const bf16x8*)&Bs[(rb * 64 + ks * 32 + fk) ^ ((rb & 7) << 3)];
      }
#pragma unroll
      for (int i = 0; i < 4; ++i)
#pragma unroll
        for (int j = 0; j < 4; ++j)
          acc[i][j] = __builtin_amdgcn_mfma_f32_16x16x32_bf16(af[i], bfr[j], acc[i][j], 0, 0, 0);
    }
    __syncthreads();
  }

  // ---- epilogue: store LOG + stage tile in LDS (32KB free now) ----
  float* ls = (float*)smem;              // [128][33]
  const int rloc = wm + (lane >> 4) * 4; // local row base
  if (wn == 0) {
#pragma unroll
    for (int j = 0; j < 3; ++j) {
      const int col = j * 16 + fr;
      if (col < 33) {
        const float bvv = bias[col];
#pragma unroll
        for (int i = 0; i < 4; ++i)
#pragma unroll
          for (int r = 0; r < 4; ++r) {
            const int row = rloc + i * 16 + r;
            const float v = acc[i][j][r] + bvv;
            LOG[(size_t)(m0 + row) * 33 + col] = v;
            ls[row * 33 + col] = v;
          }
      }
    }
  }
  __syncthreads();

  // ---- sv: one thread per row ----
  if (tid < 128) {
    const float* base = &ls[tid * 33];
    float m = base[6];
#pragma unroll
    for (int c = 7; c < 33; ++c) m = fmaxf(m, base[c]);
    float p[27], s = 0.f;
#pragma unroll
    for (int c = 0; c < 27; ++c) { p[c] = __expf(base[6 + c] - m); s += p[c]; }
    const float inv = 1.f / s;
    float vs[29];
#pragma unroll
    for (int c = 0; c < 27; ++c) vs[c] = p[c] * inv;
    vs[27] = 1.f;
    vs[28] = inv;                        // top1 = max prob
    float* outp = SV + (size_t)(m0 + tid) * 32;
#pragma unroll
    for (int o4 = 0; o4 < 8; ++o4) {
      f32x4 ov;
#pragma unroll
      for (int e = 0; e < 4; ++e) {
        const int o = o4 * 4 + e;
        float acc2 = bv[o];
        const float* w = Wv + o * 29;
#pragma unroll
        for (int c = 0; c < 29; ++c) acc2 += w[c] * vs[c];
        ov[e] = acc2;
      }
      *(f32x4*)(outp + o4 * 4) = ov;
    }
  }
}

// ---------------------------------------------------------------------------
// r16: GDf GEMM (K=512, N=28) + FUSED final-fuse epilogue. Grid (216).
// ---------------------------------------------------------------------------
__global__ __launch_bounds__(256) void gemm_gdf_fuse(
    const short* __restrict__ A, const short* __restrict__ B,
    const float* __restrict__ bias,
    const float* __restrict__ LOG, float* __restrict__ out) {
  extern __shared__ short smem[];
  short* As = smem;
  short* Bs = smem + 8192;
  const int tid = threadIdx.x;
  const int wave = tid >> 6, lane = tid & 63;
  const int m0 = blockIdx.x * 128;
  const int srow = lane >> 3;
  const int scol = ((lane & 7) ^ srow) * 8;
  const int sr0 = wave * 32;
  const int wm = (wave >> 1) * 64, wn = (wave & 1) * 64;
  const int fr = lane & 15, fk = (lane >> 4) * 8;

  f32x4 acc[4][4] = {};
  const short* pA = A + (size_t)(m0 + sr0 + srow) * 512 + scol;
  const short* pB = B + (size_t)(sr0 + srow) * 512 + scol;
  short* lA = &As[sr0 * 64];
  short* lB = &Bs[sr0 * 64];

  for (int k0 = 0; k0 < 512; k0 += 64) {
#pragma unroll
    for (int g = 0; g < 4; ++g) {
      GLDS(pA + k0 + g * 8 * 512, lA + g * 512);
      GLDS(pB + k0 + g * 8 * 512, lB + g * 512);
    }
    __syncthreads();
#pragma unroll
    for (int ks = 0; ks < 2; ++ks) {
      bf16x8 af[4], bfr[4];
#pragma unroll
      for (int t = 0; t < 4; ++t) {
        const int ra = wm + t * 16 + fr;
        const int rb = wn + t * 16 + fr;
        af[t]  = *(const bf16x8*)&As[(ra * 64 + ks * 32 + fk) ^ ((ra & 7) << 3)];
        bfr[t] = *(const bf16x8*)&Bs[(rb * 64 + ks * 32 + fk) ^ ((rb & 7) << 3)];
      }
#pragma unroll
      for (int i = 0; i < 4; ++i)
#pragma unroll
        for (int j = 0; j < 4; ++j)
          acc[i][j] = __builtin_amdgcn_mfma_f32_16x16x32_bf16(af[i], bfr[j], acc[i][j], 0, 0, 0);
    }
    __syncthreads();
  }

  // ---- epilogue: stage GDf tile [128][28] in LDS ----
  float* ls = (float*)smem;
  const int rloc = wm + (lane >> 4) * 4;
  if (wn == 0) {
#pragma unroll
    for (int j = 0; j < 2; ++j) {
      const int col = j * 16 + fr;
      if (col < 28) {
        const float bvv = bias[col];
#pragma unroll
        for (int i = 0; i < 4; ++i)
#pragma unroll
          for (int r = 0; r < 4; ++r) {
            const int row = rloc + i * 16 + r;
            ls[row * 28 + col] = acc[i][j][r] + bvv;
          }
      }
    }
  }
  __syncthreads();

  // ---- fuse: out[row, 0..32] = LOG +/- 0.1 * gate * delta ----
  for (int idx = tid; idx < 128 * 33; idx += 256) {
    const int row = idx / 33;
    const int c = idx - row * 33;
    float v = LOG[(size_t)(m0 + row) * 33 + c];
    if (c >= 6) {
      const float gate = sigmoidf_(ls[row * 28]);
      v += 0.1f * gate * ls[row * 28 + (c - 5)];
    }
    out[(size_t)(m0 + row) * 33 + c] = v;
  }
}

// ---------------------------------------------------------------------------
// Combined activation + weight conversion r15: 8-wide vectorized big regions.
// ---------------------------------------------------------------------------
__global__ __launch_bounds__(256) void conv_all(
    const float* __restrict__ inputs, const float* __restrict__ hidden,
    const float* __restrict__ W1, const float* __restrict__ Wih,
    const float* __restrict__ Whh, const float* __restrict__ Wp1,
    const float* __restrict__ Wp2, const float* __restrict__ Wq,
    const float* __restrict__ Wk, const float* __restrict__ Wg1,
    const float* __restrict__ Wd1, const float* __restrict__ Wg2,
    const float* __restrict__ Wd2, const float* __restrict__ bp1,
    const float* __restrict__ bq, const float* __restrict__ bg1,
    const float* __restrict__ bd1, const float* __restrict__ bg2,
    const float* __restrict__ bd2,
    short* __restrict__ xin, short* __restrict__ hid,
    short* __restrict__ w1w, short* __restrict__ wihw, short* __restrict__ whhw,
    short* __restrict__ wp2w, short* __restrict__ wpqk, short* __restrict__ wgdw,
    short* __restrict__ wfw, float* __restrict__ bpqkb, float* __restrict__ bgd,
    float* __restrict__ bf2v) {
  int idx = blockIdx.x * 256 + threadIdx.x;
  // ---- XIN 8-wide: rows of 352 = 44 chunks; src row stride 322 (8B align) --
  if (idx < ROWS * 44) {
    const int row = idx / 44, q = idx - row * 44;
    const int c0 = q * 8;
    short8 o;
    if (c0 <= 312) {                       // c0+7 <= 319 < 322: all valid
      const float* src = inputs + (size_t)row * 322 + c0;
      const f32x4u a = *(const f32x4u*)src;
      const f32x4u bvv = *(const f32x4u*)(src + 4);
#pragma unroll
      for (int e = 0; e < 4; ++e) { o[e] = f2bf(a[e]); o[4 + e] = f2bf(bvv[e]); }
    } else if (c0 == 320) {                // 320,321 valid, rest pad
      const float* src = inputs + (size_t)row * 322 + 320;
      o = (short8)0;
      o[0] = f2bf(src[0]); o[1] = f2bf(src[1]);
    } else {
      o = (short8)0;
    }
    *(short8*)(xin + (size_t)row * 352 + c0) = o;
    return;
  }
  idx -= ROWS * 44;
  // ---- HID 8-wide: 256/row, fully aligned ----
  if (idx < ROWS * 32) {
    const float* src = hidden + (size_t)idx * 8;
    const f32x4 a = *(const f32x4*)src;
    const f32x4 bvv = *(const f32x4*)(src + 4);
    short8 o;
#pragma unroll
    for (int e = 0; e < 4; ++e) { o[e] = f2bf(a[e]); o[4 + e] = f2bf(bvv[e]); }
    *(short8*)(hid + (size_t)idx * 8) = o;
    return;
  }
  idx -= ROWS * 32;
  // ---- WIH 8-wide (768x256 = 196608 el = 24576 chunks) ----
  if (idx < 24576) {
    const float* src = Wih + (size_t)idx * 8;
    const f32x4 a = *(const f32x4*)src;
    const f32x4 bvv = *(const f32x4*)(src + 4);
    short8 o;
#pragma unroll
    for (int e = 0; e < 4; ++e) { o[e] = f2bf(a[e]); o[4 + e] = f2bf(bvv[e]); }
    *(short8*)(wihw + (size_t)idx * 8) = o;
    return;
  }
  idx -= 24576;
  // ---- WHH 8-wide ----
  if (idx < 24576) {
    const float* src = Whh + (size_t)idx * 8;
    const f32x4 a = *(const f32x4*)src;
    const f32x4 bvv = *(const f32x4*)(src + 4);
    short8 o;
#pragma unroll
    for (int e = 0; e < 4; ++e) { o[e] = f2bf(a[e]); o[4 + e] = f2bf(bvv[e]); }
    *(short8*)(whhw + (size_t)idx * 8) = o;
    return;
  }
  idx -= 24576;
  // ---- scalar small regions ----
  if (idx < 90112) {
    int r = idx / 352, c = idx - r * 352;
    w1w[idx] = (c < 322) ? f2bf(W1[r * 322 + c]) : (short)0;
    return;
  }
  idx -= 90112;
  if (idx < 32768) {
    wp2w[idx] = (idx < 33 * 256) ? f2bf(Wp2[idx]) : (short)0;
    return;
  }
  idx -= 32768;
  if (idx < 131072) {           // WPQK 512x256: [Wp1; Wq; Wk_h; 0]
    int r = idx >> 8, c = idx & 255;
    short v = 0;
    if (r < 256) v = f2bf(Wp1[r * 256 + c]);
    else if (r < 320) v = f2bf(Wq[(r - 256) * 256 + c]);
    else if (r < 384) v = f2bf(Wk[(size_t)(r - 320) * 261 + c]);
    wpqk[idx] = v;
    return;
  }
  idx -= 131072;
  if (idx < 147456) {           // [Wg1 ; Wd1] : 512x288
    wgdw[idx] = (idx < 73728) ? f2bf(Wg1[idx]) : f2bf(Wd1[idx - 73728]);
    return;
  }
  idx -= 147456;
  if (idx < 65536) {            // WFW 128x512: r0 = [Wg2|0]; r1..27 = [0|Wd2]
    int r = idx >> 9, c = idx & 511;
    short v = 0;
    if (r == 0 && c < 256) v = f2bf(Wg2[c]);
    else if (r >= 1 && r < 28 && c >= 256) v = f2bf(Wd2[(r - 1) * 256 + (c - 256)]);
    wfw[idx] = v;
    return;
  }
  idx -= 65536;
  if (idx < 384) {
    bpqkb[idx] = (idx < 256) ? bp1[idx] : ((idx < 320) ? bq[idx - 256] : 0.f);
    return;
  }
  idx -= 384;
  if (idx < 512) { bgd[idx] = (idx < 256) ? bg1[idx] : bd1[idx - 256]; return; }
  idx -= 512;
  if (idx < 128)
    bf2v[idx] = (idx == 0) ? bg2[0] : ((idx < 28) ? bd2[idx - 1] : 0.f);
}

// ---------------------------------------------------------------------------
// GRU elementwise.
// ---------------------------------------------------------------------------
__global__ __launch_bounds__(256) void gru_kernel(
    const short* __restrict__ GI, const short* __restrict__ GH,
    const float* __restrict__ Hin, float* __restrict__ H,
    short* __restrict__ FUS) {
  int idx = blockIdx.x * 256 + threadIdx.x;
  int row = idx >> 6;
  int c = (idx & 63) * 4;
  const short4v gr = *(const short4v*)(GI + (size_t)row * 768 + c);
  const short4v gz = *(const short4v*)(GI + (size_t)row * 768 + 256 + c);
  const short4v gn = *(const short4v*)(GI + (size_t)row * 768 + 512 + c);
  const short4v hr = *(const short4v*)(GH + (size_t)row * 768 + c);
  const short4v hz = *(const short4v*)(GH + (size_t)row * 768 + 256 + c);
  const short4v hn = *(const short4v*)(GH + (size_t)row * 768 + 512 + c);
  const f32x4 hi = *(const f32x4*)(Hin + (size_t)row * 256 + c);
  f32x4 o;
  short4v ob;
#pragma unroll
  for (int p = 0; p < 4; ++p) {
    float r = sigmoidf_(bf2f(gr[p]) + bf2f(hr[p]));
    float z = sigmoidf_(bf2f(gz[p]) + bf2f(hz[p]));
    float n = tanhf(bf2f(gn[p]) + r * bf2f(hn[p]));
    float h = (1.f - z) * n + z * hi[p];
    o[p] = h;
    ob[p] = f2bf(h);
  }
  *(f32x4*)(H + (size_t)row * 256 + c) = o;
  *(short4v*)(FUS + (size_t)row * 288 + c) = ob;
}

// ---------------------------------------------------------------------------
// Attention v10 (validated r13/r14/r16: ~43us). 2 rows/wave + kh in regs.
// ---------------------------------------------------------------------------
__global__ __launch_bounds__(256) void attn8_kernel(
    const float* __restrict__ QK, const float* __restrict__ rel,
    const float* __restrict__ Wk, const float* __restrict__ bk,
    const float* __restrict__ SV, const float* __restrict__ null_key,
    const float* __restrict__ null_value, const float* __restrict__ ln_g,
    const float* __restrict__ ln_b, short* __restrict__ FUS) {
  const int b = blockIdx.x;
  const int y = blockIdx.y;             // 0..3
  const int t = threadIdx.x;
  const int wave = t >> 6, lane = t & 63;
  const int iA = y * 4 + wave;          // 0..15, always valid
  const int iB = iA + 16;               // 16..31; valid iff < 27
  const int bBv = (iB < 27);
  const int iBw = bBv ? iB : 26;

  __shared__ float sv_s[28 * 32];       // rows 0..26 = SV, row 27 = null_value
  __shared__ float wkr_s[320];
  __shared__ float bk_s[64], nk_s[64];
  __shared__ float lng_s[32], lnb_s[32];
  __shared__ float q_s[4][2][64];
  __shared__ float qws_s[4][2][28];
  __shared__ float s_row[4][2][112];

  // ---- block stage ----
  for (int idx = t; idx < 27 * 32; idx += 256)
    sv_s[idx] = SV[(size_t)b * 864 + idx];
  for (int idx = t; idx < 320; idx += 256) {
    int a = idx / 5, r = idx - a * 5;
    wkr_s[idx] = Wk[(size_t)a * 261 + 256 + r];
  }
  if (t < 64) bk_s[t] = bk[t];
  else if (t < 128) nk_s[t - 64] = null_key[t - 64];
  else if (t < 160) sv_s[27 * 32 + (t - 128)] = null_value[t - 128];
  else if (t < 192) { lng_s[t - 160] = ln_g[t - 160]; lnb_s[t - 160] = ln_b[t - 160]; }
  q_s[wave][0][lane] = QK[(size_t)(b * 27 + iA) * 128 + lane];
  q_s[wave][1][lane] = QK[(size_t)(b * 27 + iBw) * 128 + lane];
  __syncthreads();

  // ---- kh registers: j0 = lane>>2 (0..15), j1 = j0+16 (16..31) ----
  const int h = lane & 3;
  const int j0 = lane >> 2;
  const int j1 = j0 + 16;
  const int j1r = (j1 < 27) ? j1 : 26;  // clamp for safe loads
  f32x4 kv0[4], kv1[4];
  {
    const float* khp0 = QK + (size_t)(b * 27 + j0) * 128 + 64 + h * 16;
    const float* khp1 = QK + (size_t)(b * 27 + j1r) * 128 + 64 + h * 16;
#pragma unroll
    for (int c = 0; c < 4; ++c) kv0[c] = *(const f32x4*)(khp0 + c * 4);
#pragma unroll
    for (int c = 0; c < 4; ++c) kv1[c] = *(const f32x4*)(khp1 + c * 4);
  }

  // ---- qws BOTH rows in one pass: lanes 0..27 row A, lanes 32..59 row B ----
  {
    const int s = lane >> 5;
    const int ls = lane & 31;
    if (ls < 28) {
      float acc = 0.f;
      const float* q = q_s[wave][s];
      if (ls < 20) {
        const int qh = ls / 5, r = ls - qh * 5;
#pragma unroll
        for (int d = 0; d < 16; ++d)
          acc += q[qh * 16 + d] * wkr_s[(qh * 16 + d) * 5 + r];
      } else if (ls < 24) {
        const int qh = ls - 20;
#pragma unroll
        for (int d = 0; d < 16; ++d)
          acc += q[qh * 16 + d] * bk_s[qh * 16 + d];
      } else {
        const int qh = ls - 24;
#pragma unroll
        for (int d = 0; d < 16; ++d)
          acc += q[qh * 16 + d] * nk_s[qh * 16 + d];
      }
      qws_s[wave][s][ls] = acc;
    }
  }
  __builtin_amdgcn_wave_barrier();

  // ---- per-lane coefficients for h = lane&3, both rows ----
  float qw[2][5], qbk[2], qnull[2];
  f32x4 qreg[2][4];
#pragma unroll
  for (int s = 0; s < 2; ++s) {
#pragma unroll
    for (int r = 0; r < 5; ++r) qw[s][r] = qws_s[wave][s][h * 5 + r];
    qbk[s]   = qws_s[wave][s][20 + h];
    qnull[s] = qws_s[wave][s][24 + h];
#pragma unroll
    for (int c = 0; c < 4; ++c)
      qreg[s][c] = *(const f32x4*)&q_s[wave][s][h * 16 + c * 4];
  }
  const float* relA = rel + (size_t)(b * 27 + iA) * 135;
  const float* relB = rel + (size_t)(b * 27 + iBw) * 135;

  // ---- scores: kh from registers, shared across both rows ----
#pragma unroll
  for (int s = 0; s < 2; ++s) {
    const int ii = s ? iB : iA;
    const float* rl = s ? relB : relA;
    float a0 = qbk[s];
#pragma unroll
    for (int c = 0; c < 4; ++c)
#pragma unroll
      for (int e = 0; e < 4; ++e) a0 += qreg[s][c][e] * kv0[c][e];
    {
      const float* rp = rl + j0 * 5;
      a0 += rp[0] * qw[s][0] + rp[1] * qw[s][1] + rp[2] * qw[s][2]
          + rp[3] * qw[s][3] + rp[4] * qw[s][4];
    }
    float sc0 = a0 * 0.25f;
    if (j0 == ii) sc0 = NEGV;
    s_row[wave][s][lane] = sc0;
    if (lane < 48) {                    // item lane+64 exists (j1 in 16..27)
      float sc1;
      if (j1 < 27) {
        float a1 = qbk[s];
#pragma unroll
        for (int c = 0; c < 4; ++c)
#pragma unroll
          for (int e = 0; e < 4; ++e) a1 += qreg[s][c][e] * kv1[c][e];
        const float* rp = rl + j1 * 5;
        a1 += rp[0] * qw[s][0] + rp[1] * qw[s][1] + rp[2] * qw[s][2]
            + rp[3] * qw[s][3] + rp[4] * qw[s][4];
        sc1 = a1 * 0.25f;
        if (j1 == ii) sc1 = NEGV;
      } else {
        sc1 = qnull[s] * 0.25f;         // j1 == 27: null column
      }
      s_row[wave][s][lane + 64] = sc1;
    }
  }
  __builtin_amdgcn_wave_barrier();

  // ---- top4 + masked softmax: both rows, interleaved shuffle chains ----
  {
    const int g = lane >> 4;
    const int li = lane & 15;
    const int jj1 = li + 16;
    float v0[2], v1[2], w0[2], w1[2], m0[2], thr[2];
#pragma unroll
    for (int s = 0; s < 2; ++s) {
      v0[s] = s_row[wave][s][li * 4 + g];
      v1[s] = (jj1 < 28) ? s_row[wave][s][jj1 * 4 + g] : -INFINITY;
      w0[s] = v0[s]; w1[s] = v1[s];
    }
#pragma unroll
    for (int r = 0; r < 4; ++r) {
      float gm[2];
#pragma unroll
      for (int s = 0; s < 2; ++s) gm[s] = fmaxf(w0[s], w1[s]);
#pragma unroll
      for (int off = 8; off; off >>= 1) {
#pragma unroll
        for (int s = 0; s < 2; ++s) gm[s] = fmaxf(gm[s], __shfl_xor(gm[s], off));
      }
#pragma unroll
      for (int s = 0; s < 2; ++s) {
        if (r == 0) m0[s] = gm[s];
        thr[s] = gm[s];
        const unsigned long long b0 = __ballot(w0[s] == gm[s]);
        const unsigned long long b1 = __ballot(w1[s] == gm[s]);
        const unsigned seg0 = (unsigned)(b0 >> (g * 16)) & 0xFFFFu;
        const unsigned seg1 = (unsigned)(b1 >> (g * 16)) & 0xFFFFu;
        if (seg0) { if (li == __builtin_ctz(seg0)) w0[s] = -INFINITY; }
        else      { if (li == __builtin_ctz(seg1)) w1[s] = -INFINITY; }
      }
    }
    float e0[2], e1[2], inv[2];
#pragma unroll
    for (int s = 0; s < 2; ++s) {
      e0[s] = (v0[s] >= thr[s]) ? __expf(v0[s] - m0[s]) : 0.f;
      e1[s] = (jj1 < 28 && v1[s] >= thr[s]) ? __expf(v1[s] - m0[s]) : 0.f;
    }
    float ssum[2];
#pragma unroll
    for (int s = 0; s < 2; ++s) ssum[s] = e0[s] + e1[s];
#pragma unroll
    for (int off = 8; off; off >>= 1) {
#pragma unroll
      for (int s = 0; s < 2; ++s) ssum[s] += __shfl_xor(ssum[s], off);
    }
#pragma unroll
    for (int s = 0; s < 2; ++s) {
      inv[s] = 1.f / ssum[s];
      s_row[wave][s][li * 4 + g] = e0[s] * inv[s];
      if (jj1 < 28) s_row[wave][s][jj1 * 4 + g] = e1[s] * inv[s];
    }
  }
  __builtin_amdgcn_wave_barrier();

  // ---- messages + layernorm: both rows; sv_s loaded once per j ----
  {
    const int sl = lane & 31;
    const int mh = sl >> 3;
    const int jbase = (lane >> 5) * 14;   // half0: j 0..13, half1: j 14..27
    float acc[2] = {0.f, 0.f};
#pragma unroll
    for (int jj = 0; jj < 14; ++jj) {
      const int j = jbase + jj;
      const float svv = sv_s[j * 32 + sl];          // row 27 = null_value
      acc[0] += s_row[wave][0][j * 4 + mh] * svv;
      acc[1] += s_row[wave][1][j * 4 + mh] * svv;
    }
#pragma unroll
    for (int s = 0; s < 2; ++s) acc[s] += __shfl_xor(acc[s], 32);
    float sum[2] = {acc[0], acc[1]};
#pragma unroll
    for (int off = 16; off; off >>= 1) {
#pragma unroll
      for (int s = 0; s < 2; ++s) sum[s] += __shfl_xor(sum[s], off);
    }
    float d[2], sq[2];
#pragma unroll
    for (int s = 0; s < 2; ++s) { d[s] = acc[s] - sum[s] * (1.f / 32.f); sq[s] = d[s] * d[s]; }
#pragma unroll
    for (int off = 16; off; off >>= 1) {
#pragma unroll
      for (int s = 0; s < 2; ++s) sq[s] += __shfl_xor(sq[s], off);
    }
    if (lane < 32) {
      const float nvA = d[0] * rsqrtf(sq[0] * (1.f / 32.f) + 1e-5f) * lng_s[sl] + lnb_s[sl];
      FUS[(size_t)(b * 27 + iA) * 288 + 256 + sl] = f2bf(nvA);
      if (bBv) {
        const float nvB = d[1] * rsqrtf(sq[1] * (1.f / 32.f) + 1e-5f) * lng_s[sl] + lnb_s[sl];
        FUS[(size_t)(b * 27 + iB) * 288 + 256 + sl] = f2bf(nvB);
      }
    }
  }
}

// ---------------------------------------------------------------------------
extern "C" void kernel_launch(void* const* d_in, const int* in_sizes, int n_in,
                              void* d_out, int out_size, void* d_ws, size_t ws_size,
                              hipStream_t stream) {
  const float* inputs = (const float*)d_in[0];
  const float* hidden = (const float*)d_in[1];
  const float* rel    = (const float*)d_in[2];
  const float* W1  = (const float*)d_in[3];  const float* b1  = (const float*)d_in[4];
  const float* Wih = (const float*)d_in[5];  const float* bih = (const float*)d_in[6];
  const float* Whh = (const float*)d_in[7];  const float* bhh = (const float*)d_in[8];
  const float* Wp1 = (const float*)d_in[9];  const float* bp1 = (const float*)d_in[10];
  const float* Wp2 = (const float*)d_in[11]; const float* bp2 = (const float*)d_in[12];
  const float* Wq  = (const float*)d_in[13]; const float* bq  = (const float*)d_in[14];
  const float* Wk  = (const float*)d_in[15]; const float* bk  = (const float*)d_in[16];
  const float* Wv  = (const float*)d_in[17]; const float* bv  = (const float*)d_in[18];
  const float* ln_g = (const float*)d_in[19]; const float* ln_b = (const float*)d_in[20];
  const float* Wg1 = (const float*)d_in[21]; const float* bg1 = (const float*)d_in[22];
  const float* Wg2 = (const float*)d_in[23]; const float* bg2 = (const float*)d_in[24];
  const float* Wd1 = (const float*)d_in[25]; const float* bd1 = (const float*)d_in[26];
  const float* Wd2 = (const float*)d_in[27]; const float* bd2 = (const float*)d_in[28];
  const float* null_key   = (const float*)d_in[29];
  const float* null_value = (const float*)d_in[30];

  // ---- workspace layout (time-multiplexed; overlap-audited r7) ----
  char* wsb = (char*)d_ws;
  short* GIB = (short*)(wsb + 0);                    // 27648x768 bf16 (42.5MB)
  short* GDB = (short*)(wsb + 0);                    // 27648x512 bf16 (28.3MB)
  short* XINB = (short*)(wsb + 42467328);            // 27648x352 bf16
  short* GHB  = (short*)(wsb + 42467328);            // 27648x768 bf16 (all of R1)
  float* LOG  = (float*)(wsb + 42467328);            // +0       : 3.65MB
  float* QKB  = (float*)(wsb + 42467328 + 4194304);  // +4MiB    : 14.16MB -> ends +18.35MB
  float* SVB  = (float*)(wsb + 42467328 + 18874368); // +18MiB   : 3.54MB  -> ends +22.4MB
  short* XB   = (short*)(wsb + 84934656);
  short* FUS  = (short*)(wsb + 84934656);
  short* HIDB = (short*)(wsb + 84934656 + 16777216);
  short* P1B  = (short*)(wsb + 84934656 + 16777216);
  // Weights (persistent)
  char* wb = wsb + 115867648;
  short* W1W   = (short*)(wb + 0);        // 256x352
  short* WIHW  = (short*)(wb + 180224);   // 768x256
  short* WHHW  = (short*)(wb + 573440);   // 768x256
  short* WP2W  = (short*)(wb + 966656);   // 128x256
  short* WPQK  = (short*)(wb + 1032192);  // 512x256
  short* WGDW  = (short*)(wb + 1294336);  // 512x288
  short* WFW   = (short*)(wb + 1589248);  // 128x512
  float* BPQKb = (float*)(wb + 1720320);  // 384
  float* BGD   = (float*)(wb + 1721856);  // 512
  float* BF2   = (float*)(wb + 1723904);  // 128

  float* out = (float*)d_out;
  float* H   = out + (size_t)ROWS * 33;   // h output region, fp32

  // 1. bf16 conversions / packing (acts + weights, one launch; r15 8-wide)
  conv_all<<<10228, 256, 0, stream>>>(inputs, hidden,
                                      W1, Wih, Whh, Wp1, Wp2, Wq, Wk, Wg1, Wd1,
                                      Wg2, Wd2, bp1, bq, bg1, bd1, bg2, bd2,
                                      XINB, HIDB,
                                      W1W, WIHW, WHHW, WP2W, WPQK, WGDW, WFW,
                                      BPQKb, BGD, BF2);
  // 2. X = relu(inputs @ W1^T + b1)   K=352 -> 5x64 + 32 tail (48KB LDS)
  gemm_mfma<1, 1><<<dim3(216, 2), 256, 49152, stream>>>(XINB, 352, W1W, 352, b1, XB, 256, 256, 352);
  // 3. GI = X @ Wih^T + bih  AND  GH = hidden @ Whh^T + bhh (one dispatch,
  //    r22: coalesced LDS-staged C-write)
  gemm_gigh<<<dim3(216, 12), 256, 32768, stream>>>(XB, HIDB, WIHW, WHHW, bih, bhh, GIB, GHB);
  // 4. GRU -> H (fp32, d_out) + fusion[:,0:256] (bf16)
  gru_kernel<<<6912, 256, 0, stream>>>(GIB, GHB, hidden, H, FUS);
  // 5. [P1 | QK] = h @ [Wp1; Wq; Wk_h]^T + [bp1; bq; 0]   K=256
  gemm_pqk<<<dim3(216, 3), 256, 32768, stream>>>(FUS, WPQK, BPQKb, P1B, QKB);
  // 6. logits GEMM + fused sender-values
  gemm_logits_sv<<<216, 256, 32768, stream>>>(P1B, WP2W, bp2, Wv, bv, LOG, SVB);
  // 7. attention v10 -> fusion[:,256:288]
  attn8_kernel<<<dim3(1024, 4), 256, 0, stream>>>(QKB, rel, Wk, bk, SVB, null_key,
                                                  null_value, ln_g, ln_b, FUS);
  // 8. [G1 | D1] = relu(fusion @ [Wg1; Wd1]^T + [bg1; bd1])  K=288 -> 4x64+32
  gemm_mfma<1, 1><<<dim3(216, 4), 256, 49152, stream>>>(FUS, 288, WGDW, 288, BGD, GDB, 512, 512, 288);
  // 9. GDf GEMM + fused final fuse
  gemm_gdf_fuse<<<216, 256, 32768, stream>>>(GDB, WFW, BF2, LOG, out);
}